// Round 10
// baseline (417.424 us; speedup 1.0000x reference)
//
#include <hip/hip_runtime.h>
#include <cstdint>
#include <cstddef>

#define IN_DIM  768
#define NNODES  10000
#define MPAD    10240        // 32 * 320 (gemm8p) and 80 * 128 (proj GEMM)
#define NEDGES  80000
#define E_TOT   90000        // edges + self loops
#define HEADS   8
#define HID     256
#define HC      2048         // HEADS*HID
#define NEG_SLOPE 0.2f

// prep_kernel block ranges (256 threads each)
#define CVT_BLK  ((MPAD * IN_DIM / 4) / 256)          // 7680
#define CNT_BLK  ((E_TOT + 255) / 256)                // 352
#define T1_BLK   ((HC / 32) * (IN_DIM / 32))          // 1536
#define T2_BLK   ((HC / 32) * (HC / 32))              // 4096
#define TP_BLK   ((HID / 32) * (HID / 32))            // 64
#define PREP_BLK (CVT_BLK + CNT_BLK + T1_BLK + T2_BLK + TP_BLK)

typedef _Float16 __attribute__((ext_vector_type(8))) f16x8;
typedef float    __attribute__((ext_vector_type(4))) f32x4;

// ---------------------------------------------------------------------------
// edge helpers: edge ids [0,NEDGES) are real edges, [NEDGES,E_TOT) self loops
// ---------------------------------------------------------------------------
__device__ __forceinline__ int edge_src(const int* __restrict__ ei, int e) {
    return (e < NEDGES) ? ei[e] : (e - NEDGES);
}
__device__ __forceinline__ int edge_dst(const int* __restrict__ ei, int e) {
    return (e < NEDGES) ? ei[NEDGES + e] : (e - NEDGES);
}

// ---------------------------------------------------------------------------
// fused preprocessing (R9-proven): cvt + edge count + 3 weight transposes
// ---------------------------------------------------------------------------
__device__ __forceinline__ void tcvt_body(
    const float* __restrict__ W, _Float16* __restrict__ T,
    int K, int N, int bx, int by, int t)
{
    __shared__ float tile[32][33];
    int tx = t & 31, ty = t >> 5;   // 32 x 8
#pragma unroll
    for (int q = 0; q < 4; q++)
        tile[ty + q * 8][tx] = W[(size_t)(by * 32 + ty + q * 8) * N + bx * 32 + tx];
    __syncthreads();
#pragma unroll
    for (int q = 0; q < 4; q++) {
        float v = tile[tx][ty + q * 8];
        T[(size_t)(bx * 32 + ty + q * 8) * K + by * 32 + tx] = (_Float16)v;
    }
}

__global__ __launch_bounds__(256) void prep_kernel(
    const float* __restrict__ x, _Float16* __restrict__ xh,
    const int* __restrict__ ei, int* __restrict__ cnt,
    const float* __restrict__ W1, _Float16* __restrict__ W1t,
    const float* __restrict__ W2, _Float16* __restrict__ W2t,
    const float* __restrict__ Wp, _Float16* __restrict__ Wpt)
{
    int b = blockIdx.x;
    int t = threadIdx.x;
    if (b < CVT_BLK) {
        int i = b * 256 + t;
        size_t e = (size_t)i * 4;
        int r = (int)(e / IN_DIM);
        float4 v = (r < NNODES) ? *(const float4*)(x + e)
                                : make_float4(0.f, 0.f, 0.f, 0.f);
        _Float16 h4[4] = {(_Float16)v.x, (_Float16)v.y, (_Float16)v.z, (_Float16)v.w};
        *(ushort4*)(xh + e) = *(ushort4*)h4;
    } else if (b < CVT_BLK + CNT_BLK) {
        int e = (b - CVT_BLK) * 256 + t;
        if (e < E_TOT) atomicAdd(&cnt[edge_dst(ei, e)], 1);
    } else if (b < CVT_BLK + CNT_BLK + T1_BLK) {
        int idx = b - (CVT_BLK + CNT_BLK);
        tcvt_body(W1, W1t, IN_DIM, HC, idx % (HC / 32), idx / (HC / 32), t);
    } else if (b < CVT_BLK + CNT_BLK + T1_BLK + T2_BLK) {
        int idx = b - (CVT_BLK + CNT_BLK + T1_BLK);
        tcvt_body(W2, W2t, HC, HC, idx % (HC / 32), idx / (HC / 32), t);
    } else {
        int idx = b - (CVT_BLK + CNT_BLK + T1_BLK + T2_BLK);
        tcvt_body(Wp, Wpt, HID, HID, idx % (HID / 32), idx / (HID / 32), t);
    }
}

// ---------------------------------------------------------------------------
// CSR: scan + scatter (count fused into prep_kernel)
// ---------------------------------------------------------------------------
__global__ void scan_kernel(const int* __restrict__ cnt, int* __restrict__ indptr) {
    __shared__ int sums[1024];
    const int CH = 10;
    int t = threadIdx.x;
    int base = t * CH;
    int s = 0;
#pragma unroll
    for (int i = 0; i < CH; i++) { int idx = base + i; if (idx < NNODES) s += cnt[idx]; }
    sums[t] = s;
    __syncthreads();
    for (int off = 1; off < 1024; off <<= 1) {
        int v = (t >= off) ? sums[t - off] : 0;
        __syncthreads();
        sums[t] += v;
        __syncthreads();
    }
    int run = (t == 0) ? 0 : sums[t - 1];
#pragma unroll
    for (int i = 0; i < CH; i++) {
        int idx = base + i;
        if (idx < NNODES) { indptr[idx] = run; run += cnt[idx]; }
    }
    if (t == 0) indptr[NNODES] = E_TOT;
}

// stores SRC NODE IDS (not edge ids): agg reads them directly, no ei indirection
__global__ void scatter_kernel(const int* __restrict__ ei, const int* __restrict__ indptr,
                               int* __restrict__ cur, int* __restrict__ sorted) {
    int e = blockIdx.x * 256 + threadIdx.x;
    if (e < E_TOT) {
        int d = edge_dst(ei, e);
        int pos = atomicAdd(&cur[d], 1);
        sorted[indptr[d] + pos] = edge_src(ei, e);
    }
}

// ---------------------------------------------------------------------------
// 320x256 fp16 MFMA GEMM (R8 MEASURED champion, verbatim):
// Gray-code quadrants, wait-at-phase-start counted vmcnt (4/5/5/none steady |
// 4/2/0/none final), stage groups {A012 | B01 | B23 | A34}, one barrier per
// phase, NO manual lgkmcnt drain (compiler emits fine-grained lgkmcnt per
// consuming MFMA), sched_barrier(0) after each s_barrier only.
// Requires K%64==0, K/64>=2, Nn%256==0, Mpad%320==0, nwg%8==0.
// ---------------------------------------------------------------------------
__global__ __launch_bounds__(512, 2) void gemm8p_kernel(
    const _Float16* __restrict__ A, const _Float16* __restrict__ B,
    _Float16* __restrict__ C, int M, int K, int Nn)
{
    __shared__ __align__(16) _Float16 lds[2][36864];   // 2 x (20480 A + 16384 B) = 144 KiB

    const int t = threadIdx.x;
    const int w = t >> 6, lane = t & 63;
    const int fr = lane & 15, q4 = lane >> 4;
    const int wr = w >> 2, wc = w & 3;        // 2 x 4 wave grid

    // bijective XCD chunk swizzle (nwg == 256, %8 == 0)
    const int nwgx = gridDim.x;
    int wg = blockIdx.y * nwgx + blockIdx.x;
    const int cpx = (nwgx * gridDim.y) >> 3;
    wg = (wg & 7) * cpx + (wg >> 3);
    const int row0 = (wg / nwgx) * 320;
    const int col0 = (wg % nwgx) * 256;

    // staging: load q covers rows [q*64, q*64+64), thread t -> row q*64 + (t>>3),
    // 16B slot t&7; swizzled global column = ((t&7) ^ (row&7)) * 8 elements.
    const int rowt = t >> 3;
    const int scol = ((t & 7) ^ (rowt & 7)) << 3;
    const _Float16* baseA = A + (size_t)(row0 + rowt) * K + scol;
    const _Float16* baseB = B + (size_t)(col0 + rowt) * K + scol;
    const int dstw = w * 512;                 // wave-uniform elem offset in a 4096-el load block

    auto stageA = [&](int q, int kel, int bb) {
        __builtin_amdgcn_global_load_lds(
            (const __attribute__((address_space(1))) void*)(baseA + (size_t)q * 64 * K + kel),
            (__attribute__((address_space(3))) void*)&lds[bb][q * 4096 + dstw], 16, 0, 0);
    };
    auto stageB = [&](int q, int kel, int bb) {
        __builtin_amdgcn_global_load_lds(
            (const __attribute__((address_space(1))) void*)(baseB + (size_t)q * 64 * K + kel),
            (__attribute__((address_space(3))) void*)&lds[bb][20480 + q * 4096 + dstw], 16, 0, 0);
    };

    f32x4 acc[2][2][5][2];
#pragma unroll
    for (int qm = 0; qm < 2; qm++)
#pragma unroll
        for (int qn = 0; qn < 2; qn++)
#pragma unroll
            for (int mi = 0; mi < 5; mi++)
#pragma unroll
                for (int ni = 0; ni < 2; ni++)
                    acc[qm][qn][mi][ni] = {0.f, 0.f, 0.f, 0.f};

    // persistent operand fragments (Gray-code reuse across phases)
    f16x8 fa[5][2], fb[2][2];

#define LOADA(BB, QM)                                                           \
    {                                                                           \
        _Pragma("unroll")                                                       \
        for (int ks = 0; ks < 2; ks++) {                                        \
            _Pragma("unroll")                                                   \
            for (int mi = 0; mi < 5; mi++) {                                    \
                int lr = wr * 80 + mi * 16 + fr;                                \
                int sl = ((ks << 2) | q4) ^ (fr & 7);                           \
                fa[mi][ks] = *(const f16x8*)&lds[BB][(QM) * 10240 + (lr << 6) + (sl << 3)]; \
            }                                                                   \
        }                                                                       \
    }
#define LOADB(BB, QN)                                                           \
    {                                                                           \
        _Pragma("unroll")                                                       \
        for (int ks = 0; ks < 2; ks++) {                                        \
            _Pragma("unroll")                                                   \
            for (int ni = 0; ni < 2; ni++) {                                    \
                int lr = wc * 32 + ni * 16 + fr;                                \
                int sl = ((ks << 2) | q4) ^ (fr & 7);                           \
                fb[ni][ks] = *(const f16x8*)&lds[BB][20480 + (QN) * 8192 + (lr << 6) + (sl << 3)]; \
            }                                                                   \
        }                                                                       \
    }

#define PHASE(QM, QN, LOAD_STMT, STAGE_STMT, WAIT_STMT)                         \
    do {                                                                        \
        WAIT_STMT;                                                              \
        __builtin_amdgcn_s_barrier();                                           \
        __builtin_amdgcn_sched_barrier(0);                                      \
        LOAD_STMT;                                                              \
        STAGE_STMT;                                                             \
        _Pragma("unroll")                                                       \
        for (int ks = 0; ks < 2; ks++) {                                        \
            _Pragma("unroll")                                                   \
            for (int mi = 0; mi < 5; mi++) {                                    \
                _Pragma("unroll")                                               \
                for (int ni = 0; ni < 2; ni++)                                  \
                    acc[QM][QN][mi][ni] = __builtin_amdgcn_mfma_f32_16x16x32_f16(\
                        fa[mi][ks], fb[ni][ks], acc[QM][QN][mi][ni], 0, 0, 0);  \
            }                                                                   \
        }                                                                       \
    } while (0)

#define VM(N) asm volatile("s_waitcnt vmcnt(" #N ")" ::: "memory")

    // prologue: stage tile 0 in wait-group order {A012, B01, B23, A34}
    stageA(0, 0, 0); stageA(1, 0, 0); stageA(2, 0, 0);
    stageB(0, 0, 0); stageB(1, 0, 0);
    stageB(2, 0, 0); stageB(3, 0, 0);
    stageA(3, 0, 0); stageA(4, 0, 0);

    const int nT = K >> 6;
    int t0 = 0;
    for (; t0 < nT - 1; ++t0) {
        int bb = t0 & 1;
        int bn = bb ^ 1;
        int k1 = (t0 + 1) << 6;
        PHASE(0, 0, { LOADA(bb, 0); LOADB(bb, 0); },
              { stageA(0, k1, bn); stageA(1, k1, bn); stageA(2, k1, bn); },
              VM(4));
        PHASE(0, 1, { LOADB(bb, 1); },
              { stageB(0, k1, bn); stageB(1, k1, bn); },
              VM(5));
        PHASE(1, 1, { LOADA(bb, 1); },
              { stageB(2, k1, bn); stageB(3, k1, bn); },
              VM(5));
        PHASE(1, 0, { LOADB(bb, 0); },
              { stageA(3, k1, bn); stageA(4, k1, bn); },
              ((void)0));
    }
    {   // final tile: no prefetch; exact residual drains
        int bb = t0 & 1;
        PHASE(0, 0, { LOADA(bb, 0); LOADB(bb, 0); }, ((void)0), VM(4));
        PHASE(0, 1, { LOADB(bb, 1); },               ((void)0), VM(2));
        PHASE(1, 1, { LOADA(bb, 1); },               ((void)0), VM(0));
        PHASE(1, 0, { LOADB(bb, 0); },               ((void)0), ((void)0));
    }
#undef PHASE
#undef LOADA
#undef LOADB
#undef VM

    // C/D layout (measured m89/m91): col = lane&15, row = quad*4 + reg
#pragma unroll
    for (int qm = 0; qm < 2; qm++)
#pragma unroll
        for (int qn = 0; qn < 2; qn++)
#pragma unroll
            for (int mi = 0; mi < 5; mi++) {
                int mb = row0 + qm * 160 + wr * 80 + mi * 16 + q4 * 4;
#pragma unroll
                for (int ni = 0; ni < 2; ni++) {
                    int n = col0 + qn * 128 + wc * 32 + ni * 16 + fr;
#pragma unroll
                    for (int r = 0; r < 4; r++) {
                        int m = mb + r;
                        if (m < M) C[(size_t)m * Nn + n] = (_Float16)acc[qm][qn][mi][ni][r];
                    }
                }
            }
}

// ---------------------------------------------------------------------------
// fp16 MFMA GEMM (128x128, BK=32, dbuf) — kept for the small projection GEMM
// (Nn=256 is too narrow for the 8-phase kernel).  EPI=1: fp32 relu(C + bias).
// ---------------------------------------------------------------------------
template <int EPI>
__global__ __launch_bounds__(256) void mfma_gemm_kernel(
    const _Float16* __restrict__ A, const _Float16* __restrict__ B,
    void* __restrict__ Cout, const float* __restrict__ bias,
    int M, int K, int Nn, int swz)
{
    __shared__ __align__(16) _Float16 sA[2][128 * 32];   // 2 x 8 KB
    __shared__ __align__(16) _Float16 sB[2][128 * 32];   // 2 x 8 KB

    int t = threadIdx.x;
    int bx = blockIdx.x, by = blockIdx.y;
    if (swz) {                       // gridDim.x == 16 only
        int id = by * 16 + bx;
        int xcd = id & 7, slot = id >> 3;
        bx = 2 * xcd + (slot & 1);
        by = slot >> 1;
    }
    int row0 = by * 128;
    int col0 = bx * 128;

    int s0 = t, s1 = t + 256;
    int m0 = s0 >> 2, k0 = (s0 & 3) * 8;
    int m1 = s1 >> 2, k1 = (s1 & 3) * 8;
    const _Float16* a0 = A + (size_t)(row0 + m0) * K + k0;
    const _Float16* a1 = A + (size_t)(row0 + m1) * K + k1;
    const _Float16* b0 = B + (size_t)(col0 + m0) * K + k0;
    const _Float16* b1 = B + (size_t)(col0 + m1) * K + k1;

    int w = t >> 6, lane = t & 63;
    int wm = (w & 1) * 64, wn = (w >> 1) * 64;
    int fr = lane & 15, quad = lane >> 4;

    auto stage = [&](int kt, int bsel) {
        _Float16* dA0 = &sA[bsel][(w * 64) * 8];
        _Float16* dA1 = &sA[bsel][(w * 64 + 256) * 8];
        _Float16* dB0 = &sB[bsel][(w * 64) * 8];
        _Float16* dB1 = &sB[bsel][(w * 64 + 256) * 8];
        __builtin_amdgcn_global_load_lds(
            (const __attribute__((address_space(1))) void*)(a0 + kt),
            (__attribute__((address_space(3))) void*)dA0, 16, 0, 0);
        __builtin_amdgcn_global_load_lds(
            (const __attribute__((address_space(1))) void*)(a1 + kt),
            (__attribute__((address_space(3))) void*)dA1, 16, 0, 0);
        __builtin_amdgcn_global_load_lds(
            (const __attribute__((address_space(1))) void*)(b0 + kt),
            (__attribute__((address_space(3))) void*)dB0, 16, 0, 0);
        __builtin_amdgcn_global_load_lds(
            (const __attribute__((address_space(1))) void*)(b1 + kt),
            (__attribute__((address_space(3))) void*)dB1, 16, 0, 0);
    };

    f32x4 acc[4][4];
#pragma unroll
    for (int i = 0; i < 4; i++)
#pragma unroll
        for (int j = 0; j < 4; j++) acc[i][j] = {0.f, 0.f, 0.f, 0.f};

    const int nIt = K / 32;
    stage(0, 0);
    __syncthreads();

    for (int it = 0; it < nIt; ++it) {
        int cb = it & 1;
        if (it + 1 < nIt) stage((it + 1) * 32, cb ^ 1);

        f16x8 fa[4], fb[4];
#pragma unroll
        for (int i = 0; i < 4; i++) {
            fa[i] = *(const f16x8*)&sA[cb][(wm + i * 16 + fr) * 32 + quad * 8];
            fb[i] = *(const f16x8*)&sB[cb][(wn + i * 16 + fr) * 32 + quad * 8];
        }
#pragma unroll
        for (int i = 0; i < 4; i++)
#pragma unroll
            for (int j = 0; j < 4; j++)
                acc[i][j] = __builtin_amdgcn_mfma_f32_16x16x32_f16(fa[i], fb[j], acc[i][j], 0, 0, 0);

        if (it + 1 < nIt) __syncthreads();
    }

    if (EPI == 0) {
        _Float16* C = (_Float16*)Cout;
#pragma unroll
        for (int i = 0; i < 4; i++) {
            int mbase = row0 + wm + i * 16 + quad * 4;
#pragma unroll
            for (int j = 0; j < 4; j++) {
                int n = col0 + wn + j * 16 + fr;
#pragma unroll
                for (int r = 0; r < 4; r++) {
                    int m = mbase + r;
                    if (m < M) C[(size_t)m * Nn + n] = (_Float16)acc[i][j][r];
                }
            }
        }
    } else {
        float* C = (float*)Cout;
        float bv[4];
#pragma unroll
        for (int j = 0; j < 4; j++) bv[j] = bias[col0 + wn + j * 16 + fr];
#pragma unroll
        for (int i = 0; i < 4; i++) {
            int mbase = row0 + wm + i * 16 + quad * 4;
#pragma unroll
            for (int j = 0; j < 4; j++) {
                int n = col0 + wn + j * 16 + fr;
#pragma unroll
                for (int r = 0; r < 4; r++) {
                    int m = mbase + r;
                    if (m < M) C[(size_t)m * Nn + n] = fmaxf(acc[i][j][r] + bv[j], 0.f);
                }
            }
        }
    }
}

// ---------------------------------------------------------------------------
// per-node attention coefficients from fp16 H (R4/R8 champion config)
// ---------------------------------------------------------------------------
__global__ __launch_bounds__(256) void attn_kernel(
    const _Float16* __restrict__ H, const float* __restrict__ a_src,
    const float* __restrict__ a_dst, float* __restrict__ as_out,
    float* __restrict__ ad_out)
{
    int n = blockIdx.x;
    int t = threadIdx.x;
    int h = t >> 5, l = t & 31;
    f16x8 hv = *(const f16x8*)&H[(size_t)n * HC + h * HID + l * 8];
    const float* asp = a_src + h * HID + l * 8;
    const float* adp = a_dst + h * HID + l * 8;
    float sa = 0.f, sd = 0.f;
#pragma unroll
    for (int q = 0; q < 8; q++) {
        float v = (float)hv[q];
        sa = fmaf(v, asp[q], sa);
        sd = fmaf(v, adp[q], sd);
    }
#pragma unroll
    for (int o = 16; o > 0; o >>= 1) {
        sa += __shfl_xor(sa, o, 32);
        sd += __shfl_xor(sd, o, 32);
    }
    if (l == 0) { as_out[n * HEADS + h] = sa; ad_out[n * HEADS + h] = sd; }
}

// ---------------------------------------------------------------------------
// Round-10 agg: WAVE-AUTONOMOUS.  One wave per node, 4 nodes per block,
// ZERO __syncthreads.  R8/R9's 4-wave blocks lockstepped on 3-4 barriers
// around ~9-edge stages (occupancy 60-77, latency-bound); here each CU runs
// ~20+ independent node-streams.
//   lane l: holds edge l's src id (deg<=64 fast path); alpha for all 8 heads
//   computed per-lane, reduced with 64-wide shfl_xor trees, stored in a
//   2KB wave-PRIVATE LDS slab (same-wave ds order; lgkmcnt fence).  Gather:
//   lane l reads 4x16B chunks (channels c*512+l*8) of each src row, 2-edge
//   unrolled (8 loads in flight).  Head of chunk c = 2c + (l>>5); alpha read
//   from LDS broadcast.  Edges accumulate in ascending order (same FP
//   per-element op order as champion; only reduce-tree order differs).
// MODE 0: elu(sum + b1) -> fp16 [MPAD, HC]
// MODE 1: (mean over heads + b2) -> fp16 [MPAD, HID] (shfl_xor 32 reduce)
// ---------------------------------------------------------------------------
template <int MODE>
__global__ __launch_bounds__(256) void agg_kernel(
    const _Float16* __restrict__ H, const float* __restrict__ as_,
    const float* __restrict__ ad_, const float* __restrict__ bias,
    const int* __restrict__ indptr, const int* __restrict__ sorted,
    _Float16* __restrict__ outh)
{
    __shared__ float alw[4][8][64];   // wave-private alpha: 8 KB total

    const int t = threadIdx.x;
    const int w = t >> 6, lane = t & 63;
    const int n = blockIdx.x * 4 + w;

    if (n >= NNODES) {                 // pad rows for the next MFMA GEMM
        _Float16 z8[8] = {};
        if (MODE == 0) {
#pragma unroll
            for (int c = 0; c < 4; c++)
                *(f16x8*)&outh[(size_t)n * HC + c * 512 + lane * 8] = *(f16x8*)z8;
        } else {
            if (lane < 32)
                *(f16x8*)&outh[(size_t)n * HID + lane * 8] = *(f16x8*)z8;
        }
        return;
    }

    const int start = indptr[n];
    const int deg = indptr[n + 1] - start;

    // per-node ad slice (uniform across lanes; cache-broadcast)
    float4 dd0 = *(const float4*)&ad_[n * HEADS];
    float4 dd1 = *(const float4*)&ad_[n * HEADS + 4];
    const float ad8[8] = {dd0.x, dd0.y, dd0.z, dd0.w, dd1.x, dd1.y, dd1.z, dd1.w};

    float acc[4][8];
#pragma unroll
    for (int c = 0; c < 4; c++)
#pragma unroll
        for (int q = 0; q < 8; q++) acc[c][q] = 0.f;

    const int hp = lane >> 5;          // head parity (0/1) of this lane
    float* alme = &alw[w][0][0];       // this wave's private slab

    if (deg <= 64) {
        // ---- alpha: lane l owns edge l ----
        int s_l = 0;
        float p[8];
        if (lane < deg) {
            s_l = sorted[start + lane];
            float4 a0 = *(const float4*)&as_[s_l * HEADS];
            float4 a1 = *(const float4*)&as_[s_l * HEADS + 4];
            float va[8] = {a0.x, a0.y, a0.z, a0.w, a1.x, a1.y, a1.z, a1.w};
#pragma unroll
            for (int h = 0; h < 8; h++) {
                float v = va[h] + ad8[h];
                p[h] = (v >= 0.f) ? v : NEG_SLOPE * v;
            }
        } else {
#pragma unroll
            for (int h = 0; h < 8; h++) p[h] = -1e30f;
        }
#pragma unroll
        for (int h = 0; h < 8; h++) {
            float mx = p[h];
#pragma unroll
            for (int o = 32; o > 0; o >>= 1) mx = fmaxf(mx, __shfl_xor(mx, o, 64));
            float e = (lane < deg) ? expf(p[h] - mx) : 0.f;
            float sm = e;
#pragma unroll
            for (int o = 32; o > 0; o >>= 1) sm += __shfl_xor(sm, o, 64);
            alme[h * 64 + lane] = e / (sm + 1e-16f);
        }
        asm volatile("s_waitcnt lgkmcnt(0)" ::: "memory");   // same-wave w->r fence

        // ---- gather: 2-edge unrolled, 8x16B loads in flight per lane ----
        int jj = 0;
        for (; jj + 1 < deg; jj += 2) {
            int s0 = __shfl(s_l, jj, 64);
            int s1 = __shfl(s_l, jj + 1, 64);
            const _Float16* r0 = &H[(size_t)s0 * HC + lane * 8];
            const _Float16* r1 = &H[(size_t)s1 * HC + lane * 8];
            f16x8 h0[4], h1[4];
#pragma unroll
            for (int c = 0; c < 4; c++) h0[c] = *(const f16x8*)(r0 + c * 512);
#pragma unroll
            for (int c = 0; c < 4; c++) h1[c] = *(const f16x8*)(r1 + c * 512);
#pragma unroll
            for (int c = 0; c < 4; c++) {
                float a0 = alme[(2 * c + hp) * 64 + jj];
                float a1v = alme[(2 * c + hp) * 64 + jj + 1];
#pragma unroll
                for (int q = 0; q < 8; q++) acc[c][q] = fmaf(a0, (float)h0[c][q], acc[c][q]);
#pragma unroll
                for (int q = 0; q < 8; q++) acc[c][q] = fmaf(a1v, (float)h1[c][q], acc[c][q]);
            }
        }
        if (jj < deg) {
            int s0 = __shfl(s_l, jj, 64);
            const _Float16* r0 = &H[(size_t)s0 * HC + lane * 8];
#pragma unroll
            for (int c = 0; c < 4; c++) {
                f16x8 hv = *(const f16x8*)(r0 + c * 512);
                float a0 = alme[(2 * c + hp) * 64 + jj];
#pragma unroll
                for (int q = 0; q < 8; q++) acc[c][q] = fmaf(a0, (float)hv[q], acc[c][q]);
            }
        }
    } else {
        // ---- general path (deg > 64, effectively never at deg~9) ----
        float mx8[8], sm8[8];
#pragma unroll
        for (int h = 0; h < 8; h++) { mx8[h] = -1e30f; sm8[h] = 0.f; }
        for (int j = lane; j < deg; j += 64) {
            int s = sorted[start + j];
            float4 a0 = *(const float4*)&as_[s * HEADS];
            float4 a1 = *(const float4*)&as_[s * HEADS + 4];
            float va[8] = {a0.x, a0.y, a0.z, a0.w, a1.x, a1.y, a1.z, a1.w};
#pragma unroll
            for (int h = 0; h < 8; h++) {
                float v = va[h] + ad8[h];
                v = (v >= 0.f) ? v : NEG_SLOPE * v;
                mx8[h] = fmaxf(mx8[h], v);
            }
        }
#pragma unroll
        for (int h = 0; h < 8; h++)
#pragma unroll
            for (int o = 32; o > 0; o >>= 1) mx8[h] = fmaxf(mx8[h], __shfl_xor(mx8[h], o, 64));
        for (int j = lane; j < deg; j += 64) {
            int s = sorted[start + j];
            float4 a0 = *(const float4*)&as_[s * HEADS];
            float4 a1 = *(const float4*)&as_[s * HEADS + 4];
            float va[8] = {a0.x, a0.y, a0.z, a0.w, a1.x, a1.y, a1.z, a1.w};
#pragma unroll
            for (int h = 0; h < 8; h++) {
                float v = va[h] + ad8[h];
                v = (v >= 0.f) ? v : NEG_SLOPE * v;
                sm8[h] += expf(v - mx8[h]);
            }
        }
#pragma unroll
        for (int h = 0; h < 8; h++) {
#pragma unroll
            for (int o = 32; o > 0; o >>= 1) sm8[h] += __shfl_xor(sm8[h], o, 64);
            sm8[h] += 1e-16f;
        }
        for (int base = 0; base < deg; base += 64) {
            int cnt = min(64, deg - base);
            int s_l = 0;
            if (lane < cnt) {
                s_l = sorted[start + base + lane];
                float4 a0 = *(const float4*)&as_[s_l * HEADS];
                float4 a1 = *(const float4*)&as_[s_l * HEADS + 4];
                float va[8] = {a0.x, a0.y, a0.z, a0.w, a1.x, a1.y, a1.z, a1.w};
#pragma unroll
                for (int h = 0; h < 8; h++) {
                    float v = va[h] + ad8[h];
                    v = (v >= 0.f) ? v : NEG_SLOPE * v;
                    alme[h * 64 + lane] = expf(v - mx8[h]) / sm8[h];
                }
            }
            asm volatile("s_waitcnt lgkmcnt(0)" ::: "memory");
            for (int jj = 0; jj < cnt; jj++) {
                int s0 = __shfl(s_l, jj, 64);
                const _Float16* r0 = &H[(size_t)s0 * HC + lane * 8];
#pragma unroll
                for (int c = 0; c < 4; c++) {
                    f16x8 hv = *(const f16x8*)(r0 + c * 512);
                    float a0 = alme[(2 * c + hp) * 64 + jj];
#pragma unroll
                    for (int q = 0; q < 8; q++) acc[c][q] = fmaf(a0, (float)hv[q], acc[c][q]);
                }
            }
            asm volatile("s_waitcnt lgkmcnt(0)" ::: "memory");  // before slab reuse
        }
    }

    if (MODE == 0) {
#pragma unroll
        for (int c = 0; c < 4; c++) {
            _Float16 o8[8];
#pragma unroll
            for (int q = 0; q < 8; q++) {
                float v = acc[c][q] + bias[c * 512 + lane * 8 + q];
                v = (v > 0.f) ? v : expm1f(v);          // ELU (alpha=1)
                o8[q] = (_Float16)v;
            }
            *(f16x8*)&outh[(size_t)n * HC + c * 512 + lane * 8] = *(f16x8*)o8;
        }
    } else {
        // mean over heads: chunk-sum (heads 2c+hp) then pair with lane^32
        float s8[8];
#pragma unroll
        for (int q = 0; q < 8; q++)
            s8[q] = acc[0][q] + acc[1][q] + acc[2][q] + acc[3][q];
#pragma unroll
        for (int q = 0; q < 8; q++) s8[q] += __shfl_xor(s8[q], 32, 64);
        if (lane < 32) {
            int d0i = lane * 8;
            _Float16 o8[8];
#pragma unroll
            for (int q = 0; q < 8; q++)
                o8[q] = (_Float16)(s8[q] * 0.125f + bias[d0i + q]);
            *(f16x8*)&outh[(size_t)n * HID + d0i] = *(f16x8*)o8;
        }
    }
}

// ---------------------------------------------------------------------------
extern "C" void kernel_launch(void* const* d_in, const int* in_sizes, int n_in,
                              void* d_out, int out_size, void* d_ws, size_t ws_size,
                              hipStream_t stream)
{
    const float* x      = (const float*)d_in[0];
    const int*   ei     = (const int*)  d_in[1];
    const float* W1     = (const float*)d_in[2];
    const float* a_src1 = (const float*)d_in[3];
    const float* a_dst1 = (const float*)d_in[4];
    const float* b1     = (const float*)d_in[5];
    const float* W2     = (const float*)d_in[6];
    const float* a_src2 = (const float*)d_in[7];
    const float* a_dst2 = (const float*)d_in[8];
    const float* b2     = (const float*)d_in[9];
    const float* Wp     = (const float*)d_in[10];
    const float* bp     = (const float*)d_in[11];
    float* out = (float*)d_out;

    char* ws = (char*)d_ws;
    size_t off = 0;
    auto alloc = [&](size_t bytes) -> char* {
        char* p = ws + off;
        off += (bytes + 255) & ~(size_t)255;
        return p;
    };
    _Float16* Hbuf = (_Float16*)alloc((size_t)NNODES * HC * 2);          // 41 MB (H1, then H2)
    _Float16* A2   = (_Float16*)alloc((size_t)MPAD * HC * 2);            // 41.9 MB
    _Float16* W1t  = (_Float16*)alloc((size_t)HC * IN_DIM * 2);          // 3.1 MB
    _Float16* W2t  = (_Float16*)alloc((size_t)HC * HC * 2);              // 8.4 MB
    _Float16* Wpt  = (_Float16*)alloc((size_t)HID * HID * 2);            // 128 KB
    _Float16* xh   = (_Float16*)alloc((size_t)MPAD * IN_DIM * 2);        // 15.7 MB
    _Float16* out2h = (_Float16*)alloc((size_t)MPAD * HID * 2);          // 5.2 MB
    float* asad   = (float*)alloc((size_t)4 * NNODES * HEADS * sizeof(float));
    float* as1 = asad;
    float* ad1 = asad + (size_t)NNODES * HEADS;
    float* as2 = asad + (size_t)2 * NNODES * HEADS;
    float* ad2 = asad + (size_t)3 * NNODES * HEADS;
    int*   cntcur = (int*)alloc((size_t)2 * NNODES * sizeof(int));   // cnt | cur contiguous
    int*   cnt = cntcur;
    int*   cur = cntcur + NNODES;
    int*   indptr = (int*)  alloc((size_t)(NNODES + 1) * sizeof(int));
    int*   sorted = (int*)  alloc((size_t)E_TOT * sizeof(int));

    // --- one memset for cnt+cur, then fused prep (cvt + count + 3 transposes)
    hipMemsetAsync(cntcur, 0, (size_t)2 * NNODES * sizeof(int), stream);
    prep_kernel<<<PREP_BLK, 256, 0, stream>>>(x, xh, ei, cnt,
                                              W1, W1t, W2, W2t, Wp, Wpt);
    scan_kernel<<<1, 1024, 0, stream>>>(cnt, indptr);
    scatter_kernel<<<(E_TOT + 255) / 256, 256, 0, stream>>>(ei, indptr, cur, sorted);

    dim3 g8(HC / 256, MPAD / 320);   // 8 x 32 = 256 blocks = one full round

    // Layer 1: H1 = x @ W1 (8-phase 320x256 fp16 MFMA)
    gemm8p_kernel<<<g8, 512, 0, stream>>>(xh, W1t, Hbuf, NNODES, IN_DIM, HC);
    attn_kernel<<<NNODES, 256, 0, stream>>>(Hbuf, a_src1, a_dst1, as1, ad1);
    agg_kernel<0><<<MPAD / 4, 256, 0, stream>>>(Hbuf, as1, ad1, b1, indptr, sorted, A2);

    // Layer 2: H2 = elu_agg @ W2 (8-phase 320x256 fp16 MFMA)
    gemm8p_kernel<<<g8, 512, 0, stream>>>(A2, W2t, Hbuf, NNODES, HC, HC);
    attn_kernel<<<NNODES, 256, 0, stream>>>(Hbuf, a_src2, a_dst2, as2, ad2);
    agg_kernel<1><<<MPAD / 4, 256, 0, stream>>>(Hbuf, as2, ad2, b2, indptr, sorted, out2h);

    // Projection + ReLU (128^2 fp16 MFMA, bias+relu fp32 epilogue)
    dim3 gProj(HID / 128, MPAD / 128);   // 2 x 80
    mfma_gemm_kernel<1><<<gProj, 256, 0, stream>>>(out2h, Wpt, out, bp,
                                                   NNODES, HID, HID, 0);
}

// Round 11
// 396.331 us; speedup vs baseline: 1.0532x; 1.0532x over previous
//
#include <hip/hip_runtime.h>
#include <cstdint>
#include <cstddef>

#define IN_DIM  768
#define NNODES  10000
#define MPAD    10240        // 32 * 320 (gemm8p) and 80 * 128 (proj GEMM)
#define NEDGES  80000
#define E_TOT   90000        // edges + self loops
#define HEADS   8
#define HID     256
#define HC      2048         // HEADS*HID
#define NEG_SLOPE 0.2f

// prep_kernel block ranges (256 threads each)
#define CVT_BLK  ((MPAD * IN_DIM / 4) / 256)          // 7680
#define CNT_BLK  ((E_TOT + 255) / 256)                // 352
#define T1_BLK   ((HC / 32) * (IN_DIM / 32))          // 1536
#define T2_BLK   ((HC / 32) * (HC / 32))              // 4096
#define TP_BLK   ((HID / 32) * (HID / 32))            // 64
#define PREP_BLK (CVT_BLK + CNT_BLK + T1_BLK + T2_BLK + TP_BLK)

typedef _Float16 __attribute__((ext_vector_type(8))) f16x8;
typedef float    __attribute__((ext_vector_type(4))) f32x4;

// ---------------------------------------------------------------------------
// edge helpers: edge ids [0,NEDGES) are real edges, [NEDGES,E_TOT) self loops
// ---------------------------------------------------------------------------
__device__ __forceinline__ int edge_src(const int* __restrict__ ei, int e) {
    return (e < NEDGES) ? ei[e] : (e - NEDGES);
}
__device__ __forceinline__ int edge_dst(const int* __restrict__ ei, int e) {
    return (e < NEDGES) ? ei[NEDGES + e] : (e - NEDGES);
}

// ---------------------------------------------------------------------------
// fused preprocessing (R9-proven): cvt + edge count + 3 weight transposes
// ---------------------------------------------------------------------------
__device__ __forceinline__ void tcvt_body(
    const float* __restrict__ W, _Float16* __restrict__ T,
    int K, int N, int bx, int by, int t)
{
    __shared__ float tile[32][33];
    int tx = t & 31, ty = t >> 5;   // 32 x 8
#pragma unroll
    for (int q = 0; q < 4; q++)
        tile[ty + q * 8][tx] = W[(size_t)(by * 32 + ty + q * 8) * N + bx * 32 + tx];
    __syncthreads();
#pragma unroll
    for (int q = 0; q < 4; q++) {
        float v = tile[tx][ty + q * 8];
        T[(size_t)(bx * 32 + ty + q * 8) * K + by * 32 + tx] = (_Float16)v;
    }
}

__global__ __launch_bounds__(256) void prep_kernel(
    const float* __restrict__ x, _Float16* __restrict__ xh,
    const int* __restrict__ ei, int* __restrict__ cnt,
    const float* __restrict__ W1, _Float16* __restrict__ W1t,
    const float* __restrict__ W2, _Float16* __restrict__ W2t,
    const float* __restrict__ Wp, _Float16* __restrict__ Wpt)
{
    int b = blockIdx.x;
    int t = threadIdx.x;
    if (b < CVT_BLK) {
        int i = b * 256 + t;
        size_t e = (size_t)i * 4;
        int r = (int)(e / IN_DIM);
        float4 v = (r < NNODES) ? *(const float4*)(x + e)
                                : make_float4(0.f, 0.f, 0.f, 0.f);
        _Float16 h4[4] = {(_Float16)v.x, (_Float16)v.y, (_Float16)v.z, (_Float16)v.w};
        *(ushort4*)(xh + e) = *(ushort4*)h4;
    } else if (b < CVT_BLK + CNT_BLK) {
        int e = (b - CVT_BLK) * 256 + t;
        if (e < E_TOT) atomicAdd(&cnt[edge_dst(ei, e)], 1);
    } else if (b < CVT_BLK + CNT_BLK + T1_BLK) {
        int idx = b - (CVT_BLK + CNT_BLK);
        tcvt_body(W1, W1t, IN_DIM, HC, idx % (HC / 32), idx / (HC / 32), t);
    } else if (b < CVT_BLK + CNT_BLK + T1_BLK + T2_BLK) {
        int idx = b - (CVT_BLK + CNT_BLK + T1_BLK);
        tcvt_body(W2, W2t, HC, HC, idx % (HC / 32), idx / (HC / 32), t);
    } else {
        int idx = b - (CVT_BLK + CNT_BLK + T1_BLK + T2_BLK);
        tcvt_body(Wp, Wpt, HID, HID, idx % (HID / 32), idx / (HID / 32), t);
    }
}

// ---------------------------------------------------------------------------
// CSR: scan + scatter (count fused into prep_kernel)
// ---------------------------------------------------------------------------
__global__ void scan_kernel(const int* __restrict__ cnt, int* __restrict__ indptr) {
    __shared__ int sums[1024];
    const int CH = 10;
    int t = threadIdx.x;
    int base = t * CH;
    int s = 0;
#pragma unroll
    for (int i = 0; i < CH; i++) { int idx = base + i; if (idx < NNODES) s += cnt[idx]; }
    sums[t] = s;
    __syncthreads();
    for (int off = 1; off < 1024; off <<= 1) {
        int v = (t >= off) ? sums[t - off] : 0;
        __syncthreads();
        sums[t] += v;
        __syncthreads();
    }
    int run = (t == 0) ? 0 : sums[t - 1];
#pragma unroll
    for (int i = 0; i < CH; i++) {
        int idx = base + i;
        if (idx < NNODES) { indptr[idx] = run; run += cnt[idx]; }
    }
    if (t == 0) indptr[NNODES] = E_TOT;
}

// stores SRC NODE IDS (not edge ids): agg reads them directly, no ei indirection
// (R9-proven harmless piece: FETCH -3.5MB in agg)
__global__ void scatter_kernel(const int* __restrict__ ei, const int* __restrict__ indptr,
                               int* __restrict__ cur, int* __restrict__ sorted) {
    int e = blockIdx.x * 256 + threadIdx.x;
    if (e < E_TOT) {
        int d = edge_dst(ei, e);
        int pos = atomicAdd(&cur[d], 1);
        sorted[indptr[d] + pos] = edge_src(ei, e);
    }
}

// ---------------------------------------------------------------------------
// 320x256 fp16 MFMA GEMM, round-11:
//   C[M,Nn] = A[Mpad,K] @ B[Nn,K]^T,  fp16 out, guard m < M.
// Base = R8 champion (Gray-code quadrants, compiler-scheduled lgkm, no
// setprio).  Round-11 change: ONE barrier + ONE vmcnt(0) per K-tile with
// FRONT-LOADED staging -- all 9 stages for tile t+1 issue in phases 1-2 of
// tile t, so at tile t+1's vmcnt(0) the YOUNGEST load is >=2 fat phases
// (~3000 cyc) old >> L2-loaded latency (HBM rate here is 1.1 TB/s, mostly
// L2-served).  This fixes R5's failure (its youngest stage was 0-1 phases
// old) while deleting 3 barriers + 2 counted waits per tile; waves drift
// freely across the 4 quadrant phases (ds_read of one wave overlaps MFMA of
// another).  Safety: VM(0) precedes the barrier in every wave -> all staged
// slices chip-visible when any wave proceeds; reads touch only bb, stages
// only bn; tile-t reads complete before their consuming MFMAs which precede
// the next barrier -> WAR safe; sched_barrier(0) pins reads below the
// barrier; VM(0)'s "memory" clobber stops reads sinking past tile end.
// Requires K%64==0, K/64>=2, Nn%256==0, Mpad%320==0, nwg%8==0.
// ---------------------------------------------------------------------------
__global__ __launch_bounds__(512, 2) void gemm8p_kernel(
    const _Float16* __restrict__ A, const _Float16* __restrict__ B,
    _Float16* __restrict__ C, int M, int K, int Nn)
{
    __shared__ __align__(16) _Float16 lds[2][36864];   // 2 x (20480 A + 16384 B) = 144 KiB

    const int t = threadIdx.x;
    const int w = t >> 6, lane = t & 63;
    const int fr = lane & 15, q4 = lane >> 4;
    const int wr = w >> 2, wc = w & 3;        // 2 x 4 wave grid

    // bijective XCD chunk swizzle (nwg == 256, %8 == 0)
    const int nwgx = gridDim.x;
    int wg = blockIdx.y * nwgx + blockIdx.x;
    const int cpx = (nwgx * gridDim.y) >> 3;
    wg = (wg & 7) * cpx + (wg >> 3);
    const int row0 = (wg / nwgx) * 320;
    const int col0 = (wg % nwgx) * 256;

    // staging: load q covers rows [q*64, q*64+64), thread t -> row q*64 + (t>>3),
    // 16B slot t&7; swizzled global column = ((t&7) ^ (row&7)) * 8 elements.
    const int rowt = t >> 3;
    const int scol = ((t & 7) ^ (rowt & 7)) << 3;
    const _Float16* baseA = A + (size_t)(row0 + rowt) * K + scol;
    const _Float16* baseB = B + (size_t)(col0 + rowt) * K + scol;
    const int dstw = w * 512;                 // wave-uniform elem offset in a 4096-el load block

    auto stageA = [&](int q, int kel, int bb) {
        __builtin_amdgcn_global_load_lds(
            (const __attribute__((address_space(1))) void*)(baseA + (size_t)q * 64 * K + kel),
            (__attribute__((address_space(3))) void*)&lds[bb][q * 4096 + dstw], 16, 0, 0);
    };
    auto stageB = [&](int q, int kel, int bb) {
        __builtin_amdgcn_global_load_lds(
            (const __attribute__((address_space(1))) void*)(baseB + (size_t)q * 64 * K + kel),
            (__attribute__((address_space(3))) void*)&lds[bb][20480 + q * 4096 + dstw], 16, 0, 0);
    };

    f32x4 acc[2][2][5][2];
#pragma unroll
    for (int qm = 0; qm < 2; qm++)
#pragma unroll
        for (int qn = 0; qn < 2; qn++)
#pragma unroll
            for (int mi = 0; mi < 5; mi++)
#pragma unroll
                for (int ni = 0; ni < 2; ni++)
                    acc[qm][qn][mi][ni] = {0.f, 0.f, 0.f, 0.f};

    // persistent operand fragments (Gray-code reuse across phases)
    f16x8 fa[5][2], fb[2][2];

#define LOADA(BB, QM)                                                           \
    {                                                                           \
        _Pragma("unroll")                                                       \
        for (int ks = 0; ks < 2; ks++) {                                        \
            _Pragma("unroll")                                                   \
            for (int mi = 0; mi < 5; mi++) {                                    \
                int lr = wr * 80 + mi * 16 + fr;                                \
                int sl = ((ks << 2) | q4) ^ (fr & 7);                           \
                fa[mi][ks] = *(const f16x8*)&lds[BB][(QM) * 10240 + (lr << 6) + (sl << 3)]; \
            }                                                                   \
        }                                                                       \
    }
#define LOADB(BB, QN)                                                           \
    {                                                                           \
        _Pragma("unroll")                                                       \
        for (int ks = 0; ks < 2; ks++) {                                        \
            _Pragma("unroll")                                                   \
            for (int ni = 0; ni < 2; ni++) {                                    \
                int lr = wc * 32 + ni * 16 + fr;                                \
                int sl = ((ks << 2) | q4) ^ (fr & 7);                           \
                fb[ni][ks] = *(const f16x8*)&lds[BB][20480 + (QN) * 8192 + (lr << 6) + (sl << 3)]; \
            }                                                                   \
        }                                                                       \
    }
#define MFMAQ(QM, QN)                                                           \
    {                                                                           \
        _Pragma("unroll")                                                       \
        for (int ks = 0; ks < 2; ks++) {                                        \
            _Pragma("unroll")                                                   \
            for (int mi = 0; mi < 5; mi++) {                                    \
                _Pragma("unroll")                                               \
                for (int ni = 0; ni < 2; ni++)                                  \
                    acc[QM][QN][mi][ni] = __builtin_amdgcn_mfma_f32_16x16x32_f16(\
                        fa[mi][ks], fb[ni][ks], acc[QM][QN][mi][ni], 0, 0, 0);  \
            }                                                                   \
        }                                                                       \
    }

    // prologue: stage all of tile 0 (9 loads)
#pragma unroll
    for (int q = 0; q < 5; q++) stageA(q, 0, 0);
#pragma unroll
    for (int q = 0; q < 4; q++) stageB(q, 0, 0);

    const int nT = K >> 6;
    for (int t0 = 0; t0 < nT; ++t0) {
        const int bb = t0 & 1, bn = bb ^ 1, k1 = (t0 + 1) << 6;
        const bool pf = (t0 + 1 < nT);

        // single landing point per tile: all 9 stages for this tile were
        // issued >= 2 fat phases ago (front-loaded) -> vmcnt(0) is near-free.
        asm volatile("s_waitcnt vmcnt(0)" ::: "memory");
        __builtin_amdgcn_s_barrier();
        __builtin_amdgcn_sched_barrier(0);

        // phase 1: quadrant (0,0); front-load ALL A stages for t+1
        LOADA(bb, 0); LOADB(bb, 0);
        if (pf) {
            stageA(0, k1, bn); stageA(1, k1, bn); stageA(2, k1, bn);
            stageA(3, k1, bn); stageA(4, k1, bn);
        }
        MFMAQ(0, 0);

        // phase 2: quadrant (0,1); front-load ALL B stages for t+1
        LOADB(bb, 1);
        if (pf) {
            stageB(0, k1, bn); stageB(1, k1, bn);
            stageB(2, k1, bn); stageB(3, k1, bn);
        }
        MFMAQ(0, 1);

        // phase 3: quadrant (1,1) — pure compute + A reload
        LOADA(bb, 1);
        MFMAQ(1, 1);

        // phase 4: quadrant (1,0) — B0 reload + compute
        LOADB(bb, 0);
        MFMAQ(1, 0);
    }
#undef LOADA
#undef LOADB
#undef MFMAQ

    // C/D layout (measured m89/m91): col = lane&15, row = quad*4 + reg
#pragma unroll
    for (int qm = 0; qm < 2; qm++)
#pragma unroll
        for (int qn = 0; qn < 2; qn++)
#pragma unroll
            for (int mi = 0; mi < 5; mi++) {
                int mb = row0 + qm * 160 + wr * 80 + mi * 16 + q4 * 4;
#pragma unroll
                for (int ni = 0; ni < 2; ni++) {
                    int n = col0 + qn * 128 + wc * 32 + ni * 16 + fr;
#pragma unroll
                    for (int r = 0; r < 4; r++) {
                        int m = mb + r;
                        if (m < M) C[(size_t)m * Nn + n] = (_Float16)acc[qm][qn][mi][ni][r];
                    }
                }
            }
}

// ---------------------------------------------------------------------------
// fp16 MFMA GEMM (128x128, BK=32, dbuf) — kept for the small projection GEMM
// (Nn=256 is too narrow for the 8-phase kernel).  EPI=1: fp32 relu(C + bias).
// ---------------------------------------------------------------------------
template <int EPI>
__global__ __launch_bounds__(256) void mfma_gemm_kernel(
    const _Float16* __restrict__ A, const _Float16* __restrict__ B,
    void* __restrict__ Cout, const float* __restrict__ bias,
    int M, int K, int Nn, int swz)
{
    __shared__ __align__(16) _Float16 sA[2][128 * 32];   // 2 x 8 KB
    __shared__ __align__(16) _Float16 sB[2][128 * 32];   // 2 x 8 KB

    int t = threadIdx.x;
    int bx = blockIdx.x, by = blockIdx.y;
    if (swz) {                       // gridDim.x == 16 only
        int id = by * 16 + bx;
        int xcd = id & 7, slot = id >> 3;
        bx = 2 * xcd + (slot & 1);
        by = slot >> 1;
    }
    int row0 = by * 128;
    int col0 = bx * 128;

    int s0 = t, s1 = t + 256;
    int m0 = s0 >> 2, k0 = (s0 & 3) * 8;
    int m1 = s1 >> 2, k1 = (s1 & 3) * 8;
    const _Float16* a0 = A + (size_t)(row0 + m0) * K + k0;
    const _Float16* a1 = A + (size_t)(row0 + m1) * K + k1;
    const _Float16* b0 = B + (size_t)(col0 + m0) * K + k0;
    const _Float16* b1 = B + (size_t)(col0 + m1) * K + k1;

    int w = t >> 6, lane = t & 63;
    int wm = (w & 1) * 64, wn = (w >> 1) * 64;
    int fr = lane & 15, quad = lane >> 4;

    auto stage = [&](int kt, int bsel) {
        _Float16* dA0 = &sA[bsel][(w * 64) * 8];
        _Float16* dA1 = &sA[bsel][(w * 64 + 256) * 8];
        _Float16* dB0 = &sB[bsel][(w * 64) * 8];
        _Float16* dB1 = &sB[bsel][(w * 64 + 256) * 8];
        __builtin_amdgcn_global_load_lds(
            (const __attribute__((address_space(1))) void*)(a0 + kt),
            (__attribute__((address_space(3))) void*)dA0, 16, 0, 0);
        __builtin_amdgcn_global_load_lds(
            (const __attribute__((address_space(1))) void*)(a1 + kt),
            (__attribute__((address_space(3))) void*)dA1, 16, 0, 0);
        __builtin_amdgcn_global_load_lds(
            (const __attribute__((address_space(1))) void*)(b0 + kt),
            (__attribute__((address_space(3))) void*)dB0, 16, 0, 0);
        __builtin_amdgcn_global_load_lds(
            (const __attribute__((address_space(1))) void*)(b1 + kt),
            (__attribute__((address_space(3))) void*)dB1, 16, 0, 0);
    };

    f32x4 acc[4][4];
#pragma unroll
    for (int i = 0; i < 4; i++)
#pragma unroll
        for (int j = 0; j < 4; j++) acc[i][j] = {0.f, 0.f, 0.f, 0.f};

    const int nIt = K / 32;
    stage(0, 0);
    __syncthreads();

    for (int it = 0; it < nIt; ++it) {
        int cb = it & 1;
        if (it + 1 < nIt) stage((it + 1) * 32, cb ^ 1);

        f16x8 fa[4], fb[4];
#pragma unroll
        for (int i = 0; i < 4; i++) {
            fa[i] = *(const f16x8*)&sA[cb][(wm + i * 16 + fr) * 32 + quad * 8];
            fb[i] = *(const f16x8*)&sB[cb][(wn + i * 16 + fr) * 32 + quad * 8];
        }
#pragma unroll
        for (int i = 0; i < 4; i++)
#pragma unroll
            for (int j = 0; j < 4; j++)
                acc[i][j] = __builtin_amdgcn_mfma_f32_16x16x32_f16(fa[i], fb[j], acc[i][j], 0, 0, 0);

        if (it + 1 < nIt) __syncthreads();
    }

    if (EPI == 0) {
        _Float16* C = (_Float16*)Cout;
#pragma unroll
        for (int i = 0; i < 4; i++) {
            int mbase = row0 + wm + i * 16 + quad * 4;
#pragma unroll
            for (int j = 0; j < 4; j++) {
                int n = col0 + wn + j * 16 + fr;
#pragma unroll
                for (int r = 0; r < 4; r++) {
                    int m = mbase + r;
                    if (m < M) C[(size_t)m * Nn + n] = (_Float16)acc[i][j][r];
                }
            }
        }
    } else {
        float* C = (float*)Cout;
        float bv[4];
#pragma unroll
        for (int j = 0; j < 4; j++) bv[j] = bias[col0 + wn + j * 16 + fr];
#pragma unroll
        for (int i = 0; i < 4; i++) {
            int mbase = row0 + wm + i * 16 + quad * 4;
#pragma unroll
            for (int j = 0; j < 4; j++) {
                int n = col0 + wn + j * 16 + fr;
#pragma unroll
                for (int r = 0; r < 4; r++) {
                    int m = mbase + r;
                    if (m < M) C[(size_t)m * Nn + n] = fmaxf(acc[i][j][r] + bv[j], 0.f);
                }
            }
        }
    }
}

// ---------------------------------------------------------------------------
// per-node attention coefficients from fp16 H (R4/R8 champion config)
// ---------------------------------------------------------------------------
__global__ __launch_bounds__(256) void attn_kernel(
    const _Float16* __restrict__ H, const float* __restrict__ a_src,
    const float* __restrict__ a_dst, float* __restrict__ as_out,
    float* __restrict__ ad_out)
{
    int n = blockIdx.x;
    int t = threadIdx.x;
    int h = t >> 5, l = t & 31;
    f16x8 hv = *(const f16x8*)&H[(size_t)n * HC + h * HID + l * 8];
    const float* asp = a_src + h * HID + l * 8;
    const float* adp = a_dst + h * HID + l * 8;
    float sa = 0.f, sd = 0.f;
#pragma unroll
    for (int q = 0; q < 8; q++) {
        float v = (float)hv[q];
        sa = fmaf(v, asp[q], sa);
        sd = fmaf(v, adp[q], sd);
    }
#pragma unroll
    for (int o = 16; o > 0; o >>= 1) {
        sa += __shfl_xor(sa, o, 32);
        sd += __shfl_xor(sd, o, 32);
    }
    if (l == 0) { as_out[n * HEADS + h] = sa; ad_out[n * HEADS + h] = sd; }
}

// ---------------------------------------------------------------------------
// per-dst-node gather aggregation with segment softmax (R8 MEASURED champion
// structure, verbatim: 4-wave block per node, single-pass deg<=64 fast path,
// in-LDS softmax, float4 alpha reads, 4-deep gather).  R9/R10 restructures
// both regressed (merged-alpha + 8-deep: occ 77->59; wave-autonomous:
// occ 77->34).  Only change vs R8: sorted[] holds SRC IDS directly.
// MODE 0: elu(sum + b1) -> fp16 [MPAD, HC]
// MODE 1: (mean over heads + b2) -> fp16 [MPAD, HID]
// ---------------------------------------------------------------------------
template <int MODE>
__global__ __launch_bounds__(256) void agg_kernel(
    const _Float16* __restrict__ H, const float* __restrict__ as_,
    const float* __restrict__ ad_, const float* __restrict__ bias,
    const int* __restrict__ indptr, const int* __restrict__ sorted,
    _Float16* __restrict__ outh)
{
    __shared__ float m8[HEADS], d8[HEADS], adl[HEADS];
    __shared__ int   srcl[64];
    __shared__ float al2[HEADS][64];   // alpha, transposed: [head][edge]
    __shared__ float red[HC];          // MODE 1 cross-head reduction

    int n = blockIdx.x;
    int t = threadIdx.x;

    if (n >= NNODES) {                 // pad rows for the next MFMA GEMM
        if (MODE == 0) {
            _Float16 z8[8] = {};
            *(f16x8*)&outh[(size_t)n * HC + t * 8] = *(f16x8*)z8;
        } else {
            outh[(size_t)n * HID + t] = (_Float16)0.f;
        }
        return;
    }

    int start = indptr[n];
    int deg = indptr[n + 1] - start;

    if (t < HEADS) adl[t] = ad_[n * HEADS + t];
    __syncthreads();

    int hh = t >> 5, c8 = (t & 31) * 8;
    const size_t hoff = (size_t)hh * HID + c8;
    float acc[8] = {};

    if (deg <= 64) {
        // ---- fast path: one chunk, single gather of as_, in-LDS softmax ----
        if (t < deg) srcl[t] = sorted[start + t];
        __syncthreads();
        {
            int j = t & 63, h0 = t >> 6;          // h0 in 0..3
            if (j < deg) {
                int s = srcl[j];
#pragma unroll
                for (int q = 0; q < 2; q++) {
                    int hx = h0 + q * 4;
                    float v = as_[s * HEADS + hx] + adl[hx];
                    v = (v >= 0.f) ? v : NEG_SLOPE * v;
                    al2[hx][j] = v;
                }
            }
        }
        __syncthreads();
        {
            int h = t >> 5, l = t & 31;
            float mx = -1e30f;
            for (int jj = l; jj < deg; jj += 32) mx = fmaxf(mx, al2[h][jj]);
#pragma unroll
            for (int o = 16; o > 0; o >>= 1) mx = fmaxf(mx, __shfl_xor(mx, o, 32));
            float sm = 0.f;
            for (int jj = l; jj < deg; jj += 32) {
                float e = expf(al2[h][jj] - mx);
                al2[h][jj] = e;
                sm += e;
            }
#pragma unroll
            for (int o = 16; o > 0; o >>= 1) sm += __shfl_xor(sm, o, 32);
            float den = sm + 1e-16f;
            for (int jj = l; jj < deg; jj += 32) al2[h][jj] = al2[h][jj] / den;
        }
        __syncthreads();
        // ---- gather: 4 edges per step, alpha via one float4 LDS read ----
        int jj = 0;
        for (; jj + 3 < deg; jj += 4) {
            int sx0 = srcl[jj + 0], sx1 = srcl[jj + 1];
            int sx2 = srcl[jj + 2], sx3 = srcl[jj + 3];
            f16x8 h0v = *(const f16x8*)&H[(size_t)sx0 * HC + hoff];
            f16x8 h1v = *(const f16x8*)&H[(size_t)sx1 * HC + hoff];
            f16x8 h2v = *(const f16x8*)&H[(size_t)sx2 * HC + hoff];
            f16x8 h3v = *(const f16x8*)&H[(size_t)sx3 * HC + hoff];
            float4 a4 = *(const float4*)&al2[hh][jj];
#pragma unroll
            for (int q = 0; q < 8; q++) acc[q] = fmaf(a4.x, (float)h0v[q], acc[q]);
#pragma unroll
            for (int q = 0; q < 8; q++) acc[q] = fmaf(a4.y, (float)h1v[q], acc[q]);
#pragma unroll
            for (int q = 0; q < 8; q++) acc[q] = fmaf(a4.z, (float)h2v[q], acc[q]);
#pragma unroll
            for (int q = 0; q < 8; q++) acc[q] = fmaf(a4.w, (float)h3v[q], acc[q]);
        }
        for (; jj < deg; jj++) {
            int s = srcl[jj];
            f16x8 hv = *(const f16x8*)&H[(size_t)s * HC + hoff];
            float a = al2[hh][jj];
#pragma unroll
            for (int q = 0; q < 8; q++)
                acc[q] = fmaf(a, (float)hv[q], acc[q]);
        }
    } else {
        // ---- general chunked path (deg > 64, rare) ----
        int h = t >> 5, l = t & 31;
        float adh = adl[h];

        float mx = -1e30f;
        for (int j = l; j < deg; j += 32) {
            int s = sorted[start + j];
            float v = as_[s * HEADS + h] + adh;
            v = (v >= 0.f) ? v : NEG_SLOPE * v;
            mx = fmaxf(mx, v);
        }
#pragma unroll
        for (int o = 16; o > 0; o >>= 1) mx = fmaxf(mx, __shfl_xor(mx, o, 32));

        float sm = 0.f;
        for (int j = l; j < deg; j += 32) {
            int s = sorted[start + j];
            float v = as_[s * HEADS + h] + adh;
            v = (v >= 0.f) ? v : NEG_SLOPE * v;
            sm += expf(v - mx);
        }
#pragma unroll
        for (int o = 16; o > 0; o >>= 1) sm += __shfl_xor(sm, o, 32);
        if (l == 0) { m8[h] = mx; d8[h] = sm; }

        for (int base = 0; base < deg; base += 64) {
            int cntc = min(64, deg - base);
            __syncthreads();
            if (t < cntc) srcl[t] = sorted[start + base + t];
            __syncthreads();
            {
                int j = t & 63, h0 = t >> 6;
                if (j < cntc) {
                    int s = srcl[j];
#pragma unroll
                    for (int q = 0; q < 2; q++) {
                        int hx = h0 + q * 4;
                        float v = as_[s * HEADS + hx] + adl[hx];
                        v = (v >= 0.f) ? v : NEG_SLOPE * v;
                        al2[hx][j] = expf(v - m8[hx]) / (d8[hx] + 1e-16f);
                    }
                }
            }
            __syncthreads();
            int jj = 0;
            for (; jj + 3 < cntc; jj += 4) {
                int sx0 = srcl[jj + 0], sx1 = srcl[jj + 1];
                int sx2 = srcl[jj + 2], sx3 = srcl[jj + 3];
                f16x8 h0v = *(const f16x8*)&H[(size_t)sx0 * HC + hoff];
                f16x8 h1v = *(const f16x8*)&H[(size_t)sx1 * HC + hoff];
                f16x8 h2v = *(const f16x8*)&H[(size_t)sx2 * HC + hoff];
                f16x8 h3v = *(const f16x8*)&H[(size_t)sx3 * HC + hoff];
                float4 a4 = *(const float4*)&al2[hh][jj];
#pragma unroll
                for (int q = 0; q < 8; q++) acc[q] = fmaf(a4.x, (float)h0v[q], acc[q]);
#pragma unroll
                for (int q = 0; q < 8; q++) acc[q] = fmaf(a4.y, (float)h1v[q], acc[q]);
#pragma unroll
                for (int q = 0; q < 8; q++) acc[q] = fmaf(a4.z, (float)h2v[q], acc[q]);
#pragma unroll
                for (int q = 0; q < 8; q++) acc[q] = fmaf(a4.w, (float)h3v[q], acc[q]);
            }
            for (; jj < cntc; jj++) {
                int s = srcl[jj];
                f16x8 hv = *(const f16x8*)&H[(size_t)s * HC + hoff];
                float a = al2[hh][jj];
#pragma unroll
                for (int q = 0; q < 8; q++)
                    acc[q] = fmaf(a, (float)hv[q], acc[q]);
            }
        }
    }

    if (MODE == 0) {
        _Float16 o8[8];
#pragma unroll
        for (int q = 0; q < 8; q++) {
            float v = acc[q] + bias[hoff + q];
            v = (v > 0.f) ? v : expm1f(v);          // ELU (alpha=1)
            o8[q] = (_Float16)v;
        }
        *(f16x8*)&outh[(size_t)n * HC + hoff] = *(f16x8*)o8;
    } else {
#pragma unroll
        for (int q = 0; q < 8; q++) red[hoff + q] = acc[q];
        __syncthreads();
        float s = 0.f;
#pragma unroll
        for (int h2 = 0; h2 < HEADS; h2++) s += red[h2 * HID + t];
        outh[(size_t)n * HID + t] = (_Float16)(s * 0.125f + bias[t]);
    }
}

// ---------------------------------------------------------------------------
extern "C" void kernel_launch(void* const* d_in, const int* in_sizes, int n_in,
                              void* d_out, int out_size, void* d_ws, size_t ws_size,
                              hipStream_t stream)
{
    const float* x      = (const float*)d_in[0];
    const int*   ei     = (const int*)  d_in[1];
    const float* W1     = (const float*)d_in[2];
    const float* a_src1 = (const float*)d_in[3];
    const float* a_dst1 = (const float*)d_in[4];
    const float* b1     = (const float*)d_in[5];
    const float* W2     = (const float*)d_in[6];
    const float* a_src2 = (const float*)d_in[7];
    const float* a_dst2 = (const float*)d_in[8];
    const float* b2     = (const float*)d_in[9];
    const float* Wp     = (const float*)d_in[10];
    const float* bp     = (const float*)d_in[11];
    float* out = (float*)d_out;

    char* ws = (char*)d_ws;
    size_t off = 0;
    auto alloc = [&](size_t bytes) -> char* {
        char* p = ws + off;
        off += (bytes + 255) & ~(size_t)255;
        return p;
    };
    _Float16* Hbuf = (_Float16*)alloc((size_t)NNODES * HC * 2);          // 41 MB (H1, then H2)
    _Float16* A2   = (_Float16*)alloc((size_t)MPAD * HC * 2);            // 41.9 MB
    _Float16* W1t  = (_Float16*)alloc((size_t)HC * IN_DIM * 2);          // 3.1 MB
    _Float16* W2t  = (_Float16*)alloc((size_t)HC * HC * 2);              // 8.4 MB
    _Float16* Wpt  = (_Float16*)alloc((size_t)HID * HID * 2);            // 128 KB
    _Float16* xh   = (_Float16*)alloc((size_t)MPAD * IN_DIM * 2);        // 15.7 MB
    _Float16* out2h = (_Float16*)alloc((size_t)MPAD * HID * 2);          // 5.2 MB
    float* asad   = (float*)alloc((size_t)4 * NNODES * HEADS * sizeof(float));
    float* as1 = asad;
    float* ad1 = asad + (size_t)NNODES * HEADS;
    float* as2 = asad + (size_t)2 * NNODES * HEADS;
    float* ad2 = asad + (size_t)3 * NNODES * HEADS;
    int*   cntcur = (int*)alloc((size_t)2 * NNODES * sizeof(int));   // cnt | cur contiguous
    int*   cnt = cntcur;
    int*   cur = cntcur + NNODES;
    int*   indptr = (int*)  alloc((size_t)(NNODES + 1) * sizeof(int));
    int*   sorted = (int*)  alloc((size_t)E_TOT * sizeof(int));

    // --- one memset for cnt+cur, then fused prep (cvt + count + 3 transposes)
    hipMemsetAsync(cntcur, 0, (size_t)2 * NNODES * sizeof(int), stream);
    prep_kernel<<<PREP_BLK, 256, 0, stream>>>(x, xh, ei, cnt,
                                              W1, W1t, W2, W2t, Wp, Wpt);
    scan_kernel<<<1, 1024, 0, stream>>>(cnt, indptr);
    scatter_kernel<<<(E_TOT + 255) / 256, 256, 0, stream>>>(ei, indptr, cur, sorted);

    dim3 g8(HC / 256, MPAD / 320);   // 8 x 32 = 256 blocks = one full round

    // Layer 1: H1 = x @ W1 (1-barrier/tile 320x256 fp16 MFMA)
    gemm8p_kernel<<<g8, 512, 0, stream>>>(xh, W1t, Hbuf, NNODES, IN_DIM, HC);
    attn_kernel<<<NNODES, 256, 0, stream>>>(Hbuf, a_src1, a_dst1, as1, ad1);
    agg_kernel<0><<<MPAD, 256, 0, stream>>>(Hbuf, as1, ad1, b1, indptr, sorted, A2);

    // Layer 2: H2 = elu_agg @ W2 (1-barrier/tile 320x256 fp16 MFMA)
    gemm8p_kernel<<<g8, 512, 0, stream>>>(A2, W2t, Hbuf, NNODES, HC, HC);
    attn_kernel<<<NNODES, 256, 0, stream>>>(Hbuf, a_src2, a_dst2, as2, ad2);
    agg_kernel<1><<<MPAD, 256, 0, stream>>>(Hbuf, as2, ad2, b2, indptr, sorted, out2h);

    // Projection + ReLU (128^2 fp16 MFMA, bias+relu fp32 epilogue)
    dim3 gProj(HID / 128, MPAD / 128);   // 2 x 80
    mfma_gemm_kernel<1><<<gProj, 256, 0, stream>>>(out2h, Wpt, out, bp,
                                                   NNODES, HID, HID, 0);
}

// Round 12
// 389.803 us; speedup vs baseline: 1.0709x; 1.0167x over previous
//
#include <hip/hip_runtime.h>
#include <cstdint>
#include <cstddef>

#define IN_DIM  768
#define NNODES  10000
#define MPAD    10240        // 32 * 320 (gemm8p) and 80 * 128 (proj GEMM)
#define NEDGES  80000
#define E_TOT   90000        // edges + self loops
#define HEADS   8
#define HID     256
#define HC      2048         // HEADS*HID
#define NEG_SLOPE 0.2f

// prep_kernel block ranges (256 threads each)
#define CVT_BLK  ((MPAD * IN_DIM / 4) / 256)          // 7680
#define CNT_BLK  ((E_TOT + 255) / 256)                // 352
#define T1_BLK   ((HC / 32) * (IN_DIM / 32))          // 1536
#define T2_BLK   ((HC / 32) * (HC / 32))              // 4096
#define TP_BLK   ((HID / 32) * (HID / 32))            // 64
#define PREP_BLK (CVT_BLK + CNT_BLK + T1_BLK + T2_BLK + TP_BLK)

typedef _Float16 __attribute__((ext_vector_type(8))) f16x8;
typedef float    __attribute__((ext_vector_type(4))) f32x4;

// ---------------------------------------------------------------------------
// edge helpers: edge ids [0,NEDGES) are real edges, [NEDGES,E_TOT) self loops
// ---------------------------------------------------------------------------
__device__ __forceinline__ int edge_src(const int* __restrict__ ei, int e) {
    return (e < NEDGES) ? ei[e] : (e - NEDGES);
}
__device__ __forceinline__ int edge_dst(const int* __restrict__ ei, int e) {
    return (e < NEDGES) ? ei[NEDGES + e] : (e - NEDGES);
}

// ---------------------------------------------------------------------------
// fused preprocessing (R9-proven): cvt + edge count + 3 weight transposes
// ---------------------------------------------------------------------------
__device__ __forceinline__ void tcvt_body(
    const float* __restrict__ W, _Float16* __restrict__ T,
    int K, int N, int bx, int by, int t)
{
    __shared__ float tile[32][33];
    int tx = t & 31, ty = t >> 5;   // 32 x 8
#pragma unroll
    for (int q = 0; q < 4; q++)
        tile[ty + q * 8][tx] = W[(size_t)(by * 32 + ty + q * 8) * N + bx * 32 + tx];
    __syncthreads();
#pragma unroll
    for (int q = 0; q < 4; q++) {
        float v = tile[tx][ty + q * 8];
        T[(size_t)(bx * 32 + ty + q * 8) * K + by * 32 + tx] = (_Float16)v;
    }
}

__global__ __launch_bounds__(256) void prep_kernel(
    const float* __restrict__ x, _Float16* __restrict__ xh,
    const int* __restrict__ ei, int* __restrict__ cnt,
    const float* __restrict__ W1, _Float16* __restrict__ W1t,
    const float* __restrict__ W2, _Float16* __restrict__ W2t,
    const float* __restrict__ Wp, _Float16* __restrict__ Wpt)
{
    int b = blockIdx.x;
    int t = threadIdx.x;
    if (b < CVT_BLK) {
        int i = b * 256 + t;
        size_t e = (size_t)i * 4;
        int r = (int)(e / IN_DIM);
        float4 v = (r < NNODES) ? *(const float4*)(x + e)
                                : make_float4(0.f, 0.f, 0.f, 0.f);
        _Float16 h4[4] = {(_Float16)v.x, (_Float16)v.y, (_Float16)v.z, (_Float16)v.w};
        *(ushort4*)(xh + e) = *(ushort4*)h4;
    } else if (b < CVT_BLK + CNT_BLK) {
        int e = (b - CVT_BLK) * 256 + t;
        if (e < E_TOT) atomicAdd(&cnt[edge_dst(ei, e)], 1);
    } else if (b < CVT_BLK + CNT_BLK + T1_BLK) {
        int idx = b - (CVT_BLK + CNT_BLK);
        tcvt_body(W1, W1t, IN_DIM, HC, idx % (HC / 32), idx / (HC / 32), t);
    } else if (b < CVT_BLK + CNT_BLK + T1_BLK + T2_BLK) {
        int idx = b - (CVT_BLK + CNT_BLK + T1_BLK);
        tcvt_body(W2, W2t, HC, HC, idx % (HC / 32), idx / (HC / 32), t);
    } else {
        int idx = b - (CVT_BLK + CNT_BLK + T1_BLK + T2_BLK);
        tcvt_body(Wp, Wpt, HID, HID, idx % (HID / 32), idx / (HID / 32), t);
    }
}

// ---------------------------------------------------------------------------
// CSR: scan + scatter (count fused into prep_kernel)
// ---------------------------------------------------------------------------
__global__ void scan_kernel(const int* __restrict__ cnt, int* __restrict__ indptr) {
    __shared__ int sums[1024];
    const int CH = 10;
    int t = threadIdx.x;
    int base = t * CH;
    int s = 0;
#pragma unroll
    for (int i = 0; i < CH; i++) { int idx = base + i; if (idx < NNODES) s += cnt[idx]; }
    sums[t] = s;
    __syncthreads();
    for (int off = 1; off < 1024; off <<= 1) {
        int v = (t >= off) ? sums[t - off] : 0;
        __syncthreads();
        sums[t] += v;
        __syncthreads();
    }
    int run = (t == 0) ? 0 : sums[t - 1];
#pragma unroll
    for (int i = 0; i < CH; i++) {
        int idx = base + i;
        if (idx < NNODES) { indptr[idx] = run; run += cnt[idx]; }
    }
    if (t == 0) indptr[NNODES] = E_TOT;
}

// stores SRC NODE IDS (not edge ids): agg reads them directly, no ei
// indirection (R11-measured: agg 82.9 -> 80.7 us, FETCH -4MB)
__global__ void scatter_kernel(const int* __restrict__ ei, const int* __restrict__ indptr,
                               int* __restrict__ cur, int* __restrict__ sorted) {
    int e = blockIdx.x * 256 + threadIdx.x;
    if (e < E_TOT) {
        int d = edge_dst(ei, e);
        int pos = atomicAdd(&cur[d], 1);
        sorted[indptr[d] + pos] = edge_src(ei, e);
    }
}

// ---------------------------------------------------------------------------
// 320x256 fp16 MFMA GEMM (R8 MEASURED champion loop, verbatim):
// Gray-code quadrants, wait-at-phase-start COUNTED vmcnt (4/5/5/none steady |
// 4/2/0/none final), stage groups {A012 | B01 | B23 | A34}, one barrier per
// phase, NO manual lgkmcnt drain (compiler emits fine-grained lgkmcnt per
// consuming MFMA), sched_barrier(0) after each s_barrier only.
// R11's 1-barrier vmcnt(0) variant measured +4us/dispatch (drain-0 violates
// T4 even with front-loaded stages; counted-vmcnt never waits on loads
// younger than 2 phases and keeps 4-7 loads in flight across barriers).
// Requires K%64==0, K/64>=2, Nn%256==0, Mpad%320==0, nwg%8==0.
// ---------------------------------------------------------------------------
__global__ __launch_bounds__(512, 2) void gemm8p_kernel(
    const _Float16* __restrict__ A, const _Float16* __restrict__ B,
    _Float16* __restrict__ C, int M, int K, int Nn)
{
    __shared__ __align__(16) _Float16 lds[2][36864];   // 2 x (20480 A + 16384 B) = 144 KiB

    const int t = threadIdx.x;
    const int w = t >> 6, lane = t & 63;
    const int fr = lane & 15, q4 = lane >> 4;
    const int wr = w >> 2, wc = w & 3;        // 2 x 4 wave grid

    // bijective XCD chunk swizzle (nwg == 256, %8 == 0)
    const int nwgx = gridDim.x;
    int wg = blockIdx.y * nwgx + blockIdx.x;
    const int cpx = (nwgx * gridDim.y) >> 3;
    wg = (wg & 7) * cpx + (wg >> 3);
    const int row0 = (wg / nwgx) * 320;
    const int col0 = (wg % nwgx) * 256;

    // staging: load q covers rows [q*64, q*64+64), thread t -> row q*64 + (t>>3),
    // 16B slot t&7; swizzled global column = ((t&7) ^ (row&7)) * 8 elements.
    const int rowt = t >> 3;
    const int scol = ((t & 7) ^ (rowt & 7)) << 3;
    const _Float16* baseA = A + (size_t)(row0 + rowt) * K + scol;
    const _Float16* baseB = B + (size_t)(col0 + rowt) * K + scol;
    const int dstw = w * 512;                 // wave-uniform elem offset in a 4096-el load block

    auto stageA = [&](int q, int kel, int bb) {
        __builtin_amdgcn_global_load_lds(
            (const __attribute__((address_space(1))) void*)(baseA + (size_t)q * 64 * K + kel),
            (__attribute__((address_space(3))) void*)&lds[bb][q * 4096 + dstw], 16, 0, 0);
    };
    auto stageB = [&](int q, int kel, int bb) {
        __builtin_amdgcn_global_load_lds(
            (const __attribute__((address_space(1))) void*)(baseB + (size_t)q * 64 * K + kel),
            (__attribute__((address_space(3))) void*)&lds[bb][20480 + q * 4096 + dstw], 16, 0, 0);
    };

    f32x4 acc[2][2][5][2];
#pragma unroll
    for (int qm = 0; qm < 2; qm++)
#pragma unroll
        for (int qn = 0; qn < 2; qn++)
#pragma unroll
            for (int mi = 0; mi < 5; mi++)
#pragma unroll
                for (int ni = 0; ni < 2; ni++)
                    acc[qm][qn][mi][ni] = {0.f, 0.f, 0.f, 0.f};

    // persistent operand fragments (Gray-code reuse across phases)
    f16x8 fa[5][2], fb[2][2];

#define LOADA(BB, QM)                                                           \
    {                                                                           \
        _Pragma("unroll")                                                       \
        for (int ks = 0; ks < 2; ks++) {                                        \
            _Pragma("unroll")                                                   \
            for (int mi = 0; mi < 5; mi++) {                                    \
                int lr = wr * 80 + mi * 16 + fr;                                \
                int sl = ((ks << 2) | q4) ^ (fr & 7);                           \
                fa[mi][ks] = *(const f16x8*)&lds[BB][(QM) * 10240 + (lr << 6) + (sl << 3)]; \
            }                                                                   \
        }                                                                       \
    }
#define LOADB(BB, QN)                                                           \
    {                                                                           \
        _Pragma("unroll")                                                       \
        for (int ks = 0; ks < 2; ks++) {                                        \
            _Pragma("unroll")                                                   \
            for (int ni = 0; ni < 2; ni++) {                                    \
                int lr = wc * 32 + ni * 16 + fr;                                \
                int sl = ((ks << 2) | q4) ^ (fr & 7);                           \
                fb[ni][ks] = *(const f16x8*)&lds[BB][20480 + (QN) * 8192 + (lr << 6) + (sl << 3)]; \
            }                                                                   \
        }                                                                       \
    }

#define PHASE(QM, QN, LOAD_STMT, STAGE_STMT, WAIT_STMT)                         \
    do {                                                                        \
        WAIT_STMT;                                                              \
        __builtin_amdgcn_s_barrier();                                           \
        __builtin_amdgcn_sched_barrier(0);                                      \
        LOAD_STMT;                                                              \
        STAGE_STMT;                                                             \
        _Pragma("unroll")                                                       \
        for (int ks = 0; ks < 2; ks++) {                                        \
            _Pragma("unroll")                                                   \
            for (int mi = 0; mi < 5; mi++) {                                    \
                _Pragma("unroll")                                               \
                for (int ni = 0; ni < 2; ni++)                                  \
                    acc[QM][QN][mi][ni] = __builtin_amdgcn_mfma_f32_16x16x32_f16(\
                        fa[mi][ks], fb[ni][ks], acc[QM][QN][mi][ni], 0, 0, 0);  \
            }                                                                   \
        }                                                                       \
    } while (0)

#define VM(N) asm volatile("s_waitcnt vmcnt(" #N ")" ::: "memory")

    // prologue: stage tile 0 in wait-group order {A012, B01, B23, A34}
    stageA(0, 0, 0); stageA(1, 0, 0); stageA(2, 0, 0);
    stageB(0, 0, 0); stageB(1, 0, 0);
    stageB(2, 0, 0); stageB(3, 0, 0);
    stageA(3, 0, 0); stageA(4, 0, 0);

    const int nT = K >> 6;
    int t0 = 0;
    for (; t0 < nT - 1; ++t0) {
        int bb = t0 & 1;
        int bn = bb ^ 1;
        int k1 = (t0 + 1) << 6;
        PHASE(0, 0, { LOADA(bb, 0); LOADB(bb, 0); },
              { stageA(0, k1, bn); stageA(1, k1, bn); stageA(2, k1, bn); },
              VM(4));
        PHASE(0, 1, { LOADB(bb, 1); },
              { stageB(0, k1, bn); stageB(1, k1, bn); },
              VM(5));
        PHASE(1, 1, { LOADA(bb, 1); },
              { stageB(2, k1, bn); stageB(3, k1, bn); },
              VM(5));
        PHASE(1, 0, { LOADB(bb, 0); },
              { stageA(3, k1, bn); stageA(4, k1, bn); },
              ((void)0));
    }
    {   // final tile: no prefetch; exact residual drains
        int bb = t0 & 1;
        PHASE(0, 0, { LOADA(bb, 0); LOADB(bb, 0); }, ((void)0), VM(4));
        PHASE(0, 1, { LOADB(bb, 1); },               ((void)0), VM(2));
        PHASE(1, 1, { LOADA(bb, 1); },               ((void)0), VM(0));
        PHASE(1, 0, { LOADB(bb, 0); },               ((void)0), ((void)0));
    }
#undef PHASE
#undef LOADA
#undef LOADB
#undef VM

    // C/D layout (measured m89/m91): col = lane&15, row = quad*4 + reg
#pragma unroll
    for (int qm = 0; qm < 2; qm++)
#pragma unroll
        for (int qn = 0; qn < 2; qn++)
#pragma unroll
            for (int mi = 0; mi < 5; mi++) {
                int mb = row0 + qm * 160 + wr * 80 + mi * 16 + q4 * 4;
#pragma unroll
                for (int ni = 0; ni < 2; ni++) {
                    int n = col0 + qn * 128 + wc * 32 + ni * 16 + fr;
#pragma unroll
                    for (int r = 0; r < 4; r++) {
                        int m = mb + r;
                        if (m < M) C[(size_t)m * Nn + n] = (_Float16)acc[qm][qn][mi][ni][r];
                    }
                }
            }
}

// ---------------------------------------------------------------------------
// fp16 MFMA GEMM (128x128, BK=32, dbuf) — kept for the small projection GEMM
// (Nn=256 is too narrow for the 8-phase kernel).  EPI=1: fp32 relu(C + bias).
// ---------------------------------------------------------------------------
template <int EPI>
__global__ __launch_bounds__(256) void mfma_gemm_kernel(
    const _Float16* __restrict__ A, const _Float16* __restrict__ B,
    void* __restrict__ Cout, const float* __restrict__ bias,
    int M, int K, int Nn, int swz)
{
    __shared__ __align__(16) _Float16 sA[2][128 * 32];   // 2 x 8 KB
    __shared__ __align__(16) _Float16 sB[2][128 * 32];   // 2 x 8 KB

    int t = threadIdx.x;
    int bx = blockIdx.x, by = blockIdx.y;
    if (swz) {                       // gridDim.x == 16 only
        int id = by * 16 + bx;
        int xcd = id & 7, slot = id >> 3;
        bx = 2 * xcd + (slot & 1);
        by = slot >> 1;
    }
    int row0 = by * 128;
    int col0 = bx * 128;

    int s0 = t, s1 = t + 256;
    int m0 = s0 >> 2, k0 = (s0 & 3) * 8;
    int m1 = s1 >> 2, k1 = (s1 & 3) * 8;
    const _Float16* a0 = A + (size_t)(row0 + m0) * K + k0;
    const _Float16* a1 = A + (size_t)(row0 + m1) * K + k1;
    const _Float16* b0 = B + (size_t)(col0 + m0) * K + k0;
    const _Float16* b1 = B + (size_t)(col0 + m1) * K + k1;

    int w = t >> 6, lane = t & 63;
    int wm = (w & 1) * 64, wn = (w >> 1) * 64;
    int fr = lane & 15, quad = lane >> 4;

    auto stage = [&](int kt, int bsel) {
        _Float16* dA0 = &sA[bsel][(w * 64) * 8];
        _Float16* dA1 = &sA[bsel][(w * 64 + 256) * 8];
        _Float16* dB0 = &sB[bsel][(w * 64) * 8];
        _Float16* dB1 = &sB[bsel][(w * 64 + 256) * 8];
        __builtin_amdgcn_global_load_lds(
            (const __attribute__((address_space(1))) void*)(a0 + kt),
            (__attribute__((address_space(3))) void*)dA0, 16, 0, 0);
        __builtin_amdgcn_global_load_lds(
            (const __attribute__((address_space(1))) void*)(a1 + kt),
            (__attribute__((address_space(3))) void*)dA1, 16, 0, 0);
        __builtin_amdgcn_global_load_lds(
            (const __attribute__((address_space(1))) void*)(b0 + kt),
            (__attribute__((address_space(3))) void*)dB0, 16, 0, 0);
        __builtin_amdgcn_global_load_lds(
            (const __attribute__((address_space(1))) void*)(b1 + kt),
            (__attribute__((address_space(3))) void*)dB1, 16, 0, 0);
    };

    f32x4 acc[4][4];
#pragma unroll
    for (int i = 0; i < 4; i++)
#pragma unroll
        for (int j = 0; j < 4; j++) acc[i][j] = {0.f, 0.f, 0.f, 0.f};

    const int nIt = K / 32;
    stage(0, 0);
    __syncthreads();

    for (int it = 0; it < nIt; ++it) {
        int cb = it & 1;
        if (it + 1 < nIt) stage((it + 1) * 32, cb ^ 1);

        f16x8 fa[4], fb[4];
#pragma unroll
        for (int i = 0; i < 4; i++) {
            fa[i] = *(const f16x8*)&sA[cb][(wm + i * 16 + fr) * 32 + quad * 8];
            fb[i] = *(const f16x8*)&sB[cb][(wn + i * 16 + fr) * 32 + quad * 8];
        }
#pragma unroll
        for (int i = 0; i < 4; i++)
#pragma unroll
            for (int j = 0; j < 4; j++)
                acc[i][j] = __builtin_amdgcn_mfma_f32_16x16x32_f16(fa[i], fb[j], acc[i][j], 0, 0, 0);

        if (it + 1 < nIt) __syncthreads();
    }

    if (EPI == 0) {
        _Float16* C = (_Float16*)Cout;
#pragma unroll
        for (int i = 0; i < 4; i++) {
            int mbase = row0 + wm + i * 16 + quad * 4;
#pragma unroll
            for (int j = 0; j < 4; j++) {
                int n = col0 + wn + j * 16 + fr;
#pragma unroll
                for (int r = 0; r < 4; r++) {
                    int m = mbase + r;
                    if (m < M) C[(size_t)m * Nn + n] = (_Float16)acc[i][j][r];
                }
            }
        }
    } else {
        float* C = (float*)Cout;
        float bv[4];
#pragma unroll
        for (int j = 0; j < 4; j++) bv[j] = bias[col0 + wn + j * 16 + fr];
#pragma unroll
        for (int i = 0; i < 4; i++) {
            int mbase = row0 + wm + i * 16 + quad * 4;
#pragma unroll
            for (int j = 0; j < 4; j++) {
                int n = col0 + wn + j * 16 + fr;
#pragma unroll
                for (int r = 0; r < 4; r++) {
                    int m = mbase + r;
                    if (m < M) C[(size_t)m * Nn + n] = fmaxf(acc[i][j][r] + bv[j], 0.f);
                }
            }
        }
    }
}

// ---------------------------------------------------------------------------
// per-node attention coefficients from fp16 H (R4/R8 champion config)
// ---------------------------------------------------------------------------
__global__ __launch_bounds__(256) void attn_kernel(
    const _Float16* __restrict__ H, const float* __restrict__ a_src,
    const float* __restrict__ a_dst, float* __restrict__ as_out,
    float* __restrict__ ad_out)
{
    int n = blockIdx.x;
    int t = threadIdx.x;
    int h = t >> 5, l = t & 31;
    f16x8 hv = *(const f16x8*)&H[(size_t)n * HC + h * HID + l * 8];
    const float* asp = a_src + h * HID + l * 8;
    const float* adp = a_dst + h * HID + l * 8;
    float sa = 0.f, sd = 0.f;
#pragma unroll
    for (int q = 0; q < 8; q++) {
        float v = (float)hv[q];
        sa = fmaf(v, asp[q], sa);
        sd = fmaf(v, adp[q], sd);
    }
#pragma unroll
    for (int o = 16; o > 0; o >>= 1) {
        sa += __shfl_xor(sa, o, 32);
        sd += __shfl_xor(sd, o, 32);
    }
    if (l == 0) { as_out[n * HEADS + h] = sa; ad_out[n * HEADS + h] = sd; }
}

// ---------------------------------------------------------------------------
// per-dst-node gather aggregation with segment softmax (R8 champion structure
// + R11-proven src-id sorted[]: agg measured 80.7us, occ 77).
// MODE 0: elu(sum + b1) -> fp16 [MPAD, HC]
// MODE 1: (mean over heads + b2) -> fp16 [MPAD, HID]
// ---------------------------------------------------------------------------
template <int MODE>
__global__ __launch_bounds__(256) void agg_kernel(
    const _Float16* __restrict__ H, const float* __restrict__ as_,
    const float* __restrict__ ad_, const float* __restrict__ bias,
    const int* __restrict__ indptr, const int* __restrict__ sorted,
    _Float16* __restrict__ outh)
{
    __shared__ float m8[HEADS], d8[HEADS], adl[HEADS];
    __shared__ int   srcl[64];
    __shared__ float al2[HEADS][64];   // alpha, transposed: [head][edge]
    __shared__ float red[HC];          // MODE 1 cross-head reduction

    int n = blockIdx.x;
    int t = threadIdx.x;

    if (n >= NNODES) {                 // pad rows for the next MFMA GEMM
        if (MODE == 0) {
            _Float16 z8[8] = {};
            *(f16x8*)&outh[(size_t)n * HC + t * 8] = *(f16x8*)z8;
        } else {
            outh[(size_t)n * HID + t] = (_Float16)0.f;
        }
        return;
    }

    int start = indptr[n];
    int deg = indptr[n + 1] - start;

    if (t < HEADS) adl[t] = ad_[n * HEADS + t];
    __syncthreads();

    int hh = t >> 5, c8 = (t & 31) * 8;
    const size_t hoff = (size_t)hh * HID + c8;
    float acc[8] = {};

    if (deg <= 64) {
        // ---- fast path: one chunk, single gather of as_, in-LDS softmax ----
        if (t < deg) srcl[t] = sorted[start + t];
        __syncthreads();
        {
            int j = t & 63, h0 = t >> 6;          // h0 in 0..3
            if (j < deg) {
                int s = srcl[j];
#pragma unroll
                for (int q = 0; q < 2; q++) {
                    int hx = h0 + q * 4;
                    float v = as_[s * HEADS + hx] + adl[hx];
                    v = (v >= 0.f) ? v : NEG_SLOPE * v;
                    al2[hx][j] = v;
                }
            }
        }
        __syncthreads();
        {
            int h = t >> 5, l = t & 31;
            float mx = -1e30f;
            for (int jj = l; jj < deg; jj += 32) mx = fmaxf(mx, al2[h][jj]);
#pragma unroll
            for (int o = 16; o > 0; o >>= 1) mx = fmaxf(mx, __shfl_xor(mx, o, 32));
            float sm = 0.f;
            for (int jj = l; jj < deg; jj += 32) {
                float e = expf(al2[h][jj] - mx);
                al2[h][jj] = e;
                sm += e;
            }
#pragma unroll
            for (int o = 16; o > 0; o >>= 1) sm += __shfl_xor(sm, o, 32);
            float den = sm + 1e-16f;
            for (int jj = l; jj < deg; jj += 32) al2[h][jj] = al2[h][jj] / den;
        }
        __syncthreads();
        // ---- gather: 4 edges per step, alpha via one float4 LDS read ----
        int jj = 0;
        for (; jj + 3 < deg; jj += 4) {
            int sx0 = srcl[jj + 0], sx1 = srcl[jj + 1];
            int sx2 = srcl[jj + 2], sx3 = srcl[jj + 3];
            f16x8 h0v = *(const f16x8*)&H[(size_t)sx0 * HC + hoff];
            f16x8 h1v = *(const f16x8*)&H[(size_t)sx1 * HC + hoff];
            f16x8 h2v = *(const f16x8*)&H[(size_t)sx2 * HC + hoff];
            f16x8 h3v = *(const f16x8*)&H[(size_t)sx3 * HC + hoff];
            float4 a4 = *(const float4*)&al2[hh][jj];
#pragma unroll
            for (int q = 0; q < 8; q++) acc[q] = fmaf(a4.x, (float)h0v[q], acc[q]);
#pragma unroll
            for (int q = 0; q < 8; q++) acc[q] = fmaf(a4.y, (float)h1v[q], acc[q]);
#pragma unroll
            for (int q = 0; q < 8; q++) acc[q] = fmaf(a4.z, (float)h2v[q], acc[q]);
#pragma unroll
            for (int q = 0; q < 8; q++) acc[q] = fmaf(a4.w, (float)h3v[q], acc[q]);
        }
        for (; jj < deg; jj++) {
            int s = srcl[jj];
            f16x8 hv = *(const f16x8*)&H[(size_t)s * HC + hoff];
            float a = al2[hh][jj];
#pragma unroll
            for (int q = 0; q < 8; q++)
                acc[q] = fmaf(a, (float)hv[q], acc[q]);
        }
    } else {
        // ---- general chunked path (deg > 64, rare) ----
        int h = t >> 5, l = t & 31;
        float adh = adl[h];

        float mx = -1e30f;
        for (int j = l; j < deg; j += 32) {
            int s = sorted[start + j];
            float v = as_[s * HEADS + h] + adh;
            v = (v >= 0.f) ? v : NEG_SLOPE * v;
            mx = fmaxf(mx, v);
        }
#pragma unroll
        for (int o = 16; o > 0; o >>= 1) mx = fmaxf(mx, __shfl_xor(mx, o, 32));

        float sm = 0.f;
        for (int j = l; j < deg; j += 32) {
            int s = sorted[start + j];
            float v = as_[s * HEADS + h] + adh;
            v = (v >= 0.f) ? v : NEG_SLOPE * v;
            sm += expf(v - mx);
        }
#pragma unroll
        for (int o = 16; o > 0; o >>= 1) sm += __shfl_xor(sm, o, 32);
        if (l == 0) { m8[h] = mx; d8[h] = sm; }

        for (int base = 0; base < deg; base += 64) {
            int cntc = min(64, deg - base);
            __syncthreads();
            if (t < cntc) srcl[t] = sorted[start + base + t];
            __syncthreads();
            {
                int j = t & 63, h0 = t >> 6;
                if (j < cntc) {
                    int s = srcl[j];
#pragma unroll
                    for (int q = 0; q < 2; q++) {
                        int hx = h0 + q * 4;
                        float v = as_[s * HEADS + hx] + adl[hx];
                        v = (v >= 0.f) ? v : NEG_SLOPE * v;
                        al2[hx][j] = expf(v - m8[hx]) / (d8[hx] + 1e-16f);
                    }
                }
            }
            __syncthreads();
            int jj = 0;
            for (; jj + 3 < cntc; jj += 4) {
                int sx0 = srcl[jj + 0], sx1 = srcl[jj + 1];
                int sx2 = srcl[jj + 2], sx3 = srcl[jj + 3];
                f16x8 h0v = *(const f16x8*)&H[(size_t)sx0 * HC + hoff];
                f16x8 h1v = *(const f16x8*)&H[(size_t)sx1 * HC + hoff];
                f16x8 h2v = *(const f16x8*)&H[(size_t)sx2 * HC + hoff];
                f16x8 h3v = *(const f16x8*)&H[(size_t)sx3 * HC + hoff];
                float4 a4 = *(const float4*)&al2[hh][jj];
#pragma unroll
                for (int q = 0; q < 8; q++) acc[q] = fmaf(a4.x, (float)h0v[q], acc[q]);
#pragma unroll
                for (int q = 0; q < 8; q++) acc[q] = fmaf(a4.y, (float)h1v[q], acc[q]);
#pragma unroll
                for (int q = 0; q < 8; q++) acc[q] = fmaf(a4.z, (float)h2v[q], acc[q]);
#pragma unroll
                for (int q = 0; q < 8; q++) acc[q] = fmaf(a4.w, (float)h3v[q], acc[q]);
            }
            for (; jj < cntc; jj++) {
                int s = srcl[jj];
                f16x8 hv = *(const f16x8*)&H[(size_t)s * HC + hoff];
                float a = al2[hh][jj];
#pragma unroll
                for (int q = 0; q < 8; q++)
                    acc[q] = fmaf(a, (float)hv[q], acc[q]);
            }
        }
    }

    if (MODE == 0) {
        _Float16 o8[8];
#pragma unroll
        for (int q = 0; q < 8; q++) {
            float v = acc[q] + bias[hoff + q];
            v = (v > 0.f) ? v : expm1f(v);          // ELU (alpha=1)
            o8[q] = (_Float16)v;
        }
        *(f16x8*)&outh[(size_t)n * HC + hoff] = *(f16x8*)o8;
    } else {
#pragma unroll
        for (int q = 0; q < 8; q++) red[hoff + q] = acc[q];
        __syncthreads();
        float s = 0.f;
#pragma unroll
        for (int h2 = 0; h2 < HEADS; h2++) s += red[h2 * HID + t];
        outh[(size_t)n * HID + t] = (_Float16)(s * 0.125f + bias[t]);
    }
}

// ---------------------------------------------------------------------------
extern "C" void kernel_launch(void* const* d_in, const int* in_sizes, int n_in,
                              void* d_out, int out_size, void* d_ws, size_t ws_size,
                              hipStream_t stream)
{
    const float* x      = (const float*)d_in[0];
    const int*   ei     = (const int*)  d_in[1];
    const float* W1     = (const float*)d_in[2];
    const float* a_src1 = (const float*)d_in[3];
    const float* a_dst1 = (const float*)d_in[4];
    const float* b1     = (const float*)d_in[5];
    const float* W2     = (const float*)d_in[6];
    const float* a_src2 = (const float*)d_in[7];
    const float* a_dst2 = (const float*)d_in[8];
    const float* b2     = (const float*)d_in[9];
    const float* Wp     = (const float*)d_in[10];
    const float* bp     = (const float*)d_in[11];
    float* out = (float*)d_out;

    char* ws = (char*)d_ws;
    size_t off = 0;
    auto alloc = [&](size_t bytes) -> char* {
        char* p = ws + off;
        off += (bytes + 255) & ~(size_t)255;
        return p;
    };
    _Float16* Hbuf = (_Float16*)alloc((size_t)NNODES * HC * 2);          // 41 MB (H1, then H2)
    _Float16* A2   = (_Float16*)alloc((size_t)MPAD * HC * 2);            // 41.9 MB
    _Float16* W1t  = (_Float16*)alloc((size_t)HC * IN_DIM * 2);          // 3.1 MB
    _Float16* W2t  = (_Float16*)alloc((size_t)HC * HC * 2);              // 8.4 MB
    _Float16* Wpt  = (_Float16*)alloc((size_t)HID * HID * 2);            // 128 KB
    _Float16* xh   = (_Float16*)alloc((size_t)MPAD * IN_DIM * 2);        // 15.7 MB
    _Float16* out2h = (_Float16*)alloc((size_t)MPAD * HID * 2);          // 5.2 MB
    float* asad   = (float*)alloc((size_t)4 * NNODES * HEADS * sizeof(float));
    float* as1 = asad;
    float* ad1 = asad + (size_t)NNODES * HEADS;
    float* as2 = asad + (size_t)2 * NNODES * HEADS;
    float* ad2 = asad + (size_t)3 * NNODES * HEADS;
    int*   cntcur = (int*)alloc((size_t)2 * NNODES * sizeof(int));   // cnt | cur contiguous
    int*   cnt = cntcur;
    int*   cur = cntcur + NNODES;
    int*   indptr = (int*)  alloc((size_t)(NNODES + 1) * sizeof(int));
    int*   sorted = (int*)  alloc((size_t)E_TOT * sizeof(int));

    // --- one memset for cnt+cur, then fused prep (cvt + count + 3 transposes)
    hipMemsetAsync(cntcur, 0, (size_t)2 * NNODES * sizeof(int), stream);
    prep_kernel<<<PREP_BLK, 256, 0, stream>>>(x, xh, ei, cnt,
                                              W1, W1t, W2, W2t, Wp, Wpt);
    scan_kernel<<<1, 1024, 0, stream>>>(cnt, indptr);
    scatter_kernel<<<(E_TOT + 255) / 256, 256, 0, stream>>>(ei, indptr, cur, sorted);

    dim3 g8(HC / 256, MPAD / 320);   // 8 x 32 = 256 blocks = one full round

    // Layer 1: H1 = x @ W1 (R8-champion 320x256 fp16 MFMA)
    gemm8p_kernel<<<g8, 512, 0, stream>>>(xh, W1t, Hbuf, NNODES, IN_DIM, HC);
    attn_kernel<<<NNODES, 256, 0, stream>>>(Hbuf, a_src1, a_dst1, as1, ad1);
    agg_kernel<0><<<MPAD, 256, 0, stream>>>(Hbuf, as1, ad1, b1, indptr, sorted, A2);

    // Layer 2: H2 = elu_agg @ W2 (R8-champion 320x256 fp16 MFMA)
    gemm8p_kernel<<<g8, 512, 0, stream>>>(A2, W2t, Hbuf, NNODES, HC, HC);
    attn_kernel<<<NNODES, 256, 0, stream>>>(Hbuf, a_src2, a_dst2, as2, ad2);
    agg_kernel<1><<<MPAD, 256, 0, stream>>>(Hbuf, as2, ad2, b2, indptr, sorted, out2h);

    // Projection + ReLU (128^2 fp16 MFMA, bias+relu fp32 epilogue)
    dim3 gProj(HID / 128, MPAD / 128);   // 2 x 80
    mfma_gemm_kernel<1><<<gProj, 256, 0, stream>>>(out2h, Wpt, out, bp,
                                                   NNODES, HID, HID, 0);
}

// Round 13
// 386.913 us; speedup vs baseline: 1.0789x; 1.0075x over previous
//
#include <hip/hip_runtime.h>
#include <cstdint>
#include <cstddef>

#define IN_DIM  768
#define NNODES  10000
#define MPAD    10240        // 32 * 320 (gemm8p) and 80 * 128 (proj GEMM)
#define NEDGES  80000
#define E_TOT   90000        // edges + self loops
#define HEADS   8
#define HID     256
#define HC      2048         // HEADS*HID
#define NEG_SLOPE 0.2f

// prep_kernel block ranges (256 threads each)
#define CVT_BLK  ((MPAD * IN_DIM / 4) / 256)          // 7680
#define CNT_BLK  ((E_TOT + 255) / 256)                // 352
#define T1_BLK   ((HC / 32) * (IN_DIM / 32))          // 1536
#define T2_BLK   ((HC / 32) * (HC / 32))              // 4096
#define TP_BLK   ((HID / 32) * (HID / 32))            // 64
#define PREP_BLK (CVT_BLK + CNT_BLK + T1_BLK + T2_BLK + TP_BLK)

typedef _Float16 __attribute__((ext_vector_type(8))) f16x8;
typedef float    __attribute__((ext_vector_type(4))) f32x4;

// ---------------------------------------------------------------------------
// edge helpers: edge ids [0,NEDGES) are real edges, [NEDGES,E_TOT) self loops
// ---------------------------------------------------------------------------
__device__ __forceinline__ int edge_src(const int* __restrict__ ei, int e) {
    return (e < NEDGES) ? ei[e] : (e - NEDGES);
}
__device__ __forceinline__ int edge_dst(const int* __restrict__ ei, int e) {
    return (e < NEDGES) ? ei[NEDGES + e] : (e - NEDGES);
}

// ---------------------------------------------------------------------------
// fused preprocessing (R9-proven): cvt + edge count + 3 weight transposes
// ---------------------------------------------------------------------------
__device__ __forceinline__ void tcvt_body(
    const float* __restrict__ W, _Float16* __restrict__ T,
    int K, int N, int bx, int by, int t)
{
    __shared__ float tile[32][33];
    int tx = t & 31, ty = t >> 5;   // 32 x 8
#pragma unroll
    for (int q = 0; q < 4; q++)
        tile[ty + q * 8][tx] = W[(size_t)(by * 32 + ty + q * 8) * N + bx * 32 + tx];
    __syncthreads();
#pragma unroll
    for (int q = 0; q < 4; q++) {
        float v = tile[tx][ty + q * 8];
        T[(size_t)(bx * 32 + ty + q * 8) * K + by * 32 + tx] = (_Float16)v;
    }
}

__global__ __launch_bounds__(256) void prep_kernel(
    const float* __restrict__ x, _Float16* __restrict__ xh,
    const int* __restrict__ ei, int* __restrict__ cnt,
    const float* __restrict__ W1, _Float16* __restrict__ W1t,
    const float* __restrict__ W2, _Float16* __restrict__ W2t,
    const float* __restrict__ Wp, _Float16* __restrict__ Wpt)
{
    int b = blockIdx.x;
    int t = threadIdx.x;
    if (b < CVT_BLK) {
        int i = b * 256 + t;
        size_t e = (size_t)i * 4;
        int r = (int)(e / IN_DIM);
        float4 v = (r < NNODES) ? *(const float4*)(x + e)
                                : make_float4(0.f, 0.f, 0.f, 0.f);
        _Float16 h4[4] = {(_Float16)v.x, (_Float16)v.y, (_Float16)v.z, (_Float16)v.w};
        *(ushort4*)(xh + e) = *(ushort4*)h4;
    } else if (b < CVT_BLK + CNT_BLK) {
        int e = (b - CVT_BLK) * 256 + t;
        if (e < E_TOT) atomicAdd(&cnt[edge_dst(ei, e)], 1);
    } else if (b < CVT_BLK + CNT_BLK + T1_BLK) {
        int idx = b - (CVT_BLK + CNT_BLK);
        tcvt_body(W1, W1t, IN_DIM, HC, idx % (HC / 32), idx / (HC / 32), t);
    } else if (b < CVT_BLK + CNT_BLK + T1_BLK + T2_BLK) {
        int idx = b - (CVT_BLK + CNT_BLK + T1_BLK);
        tcvt_body(W2, W2t, HC, HC, idx % (HC / 32), idx / (HC / 32), t);
    } else {
        int idx = b - (CVT_BLK + CNT_BLK + T1_BLK + T2_BLK);
        tcvt_body(Wp, Wpt, HID, HID, idx % (HID / 32), idx / (HID / 32), t);
    }
}

// ---------------------------------------------------------------------------
// CSR: scan + scatter (count fused into prep_kernel)
// ---------------------------------------------------------------------------
__global__ void scan_kernel(const int* __restrict__ cnt, int* __restrict__ indptr) {
    __shared__ int sums[1024];
    const int CH = 10;
    int t = threadIdx.x;
    int base = t * CH;
    int s = 0;
#pragma unroll
    for (int i = 0; i < CH; i++) { int idx = base + i; if (idx < NNODES) s += cnt[idx]; }
    sums[t] = s;
    __syncthreads();
    for (int off = 1; off < 1024; off <<= 1) {
        int v = (t >= off) ? sums[t - off] : 0;
        __syncthreads();
        sums[t] += v;
        __syncthreads();
    }
    int run = (t == 0) ? 0 : sums[t - 1];
#pragma unroll
    for (int i = 0; i < CH; i++) {
        int idx = base + i;
        if (idx < NNODES) { indptr[idx] = run; run += cnt[idx]; }
    }
    if (t == 0) indptr[NNODES] = E_TOT;
}

// stores SRC NODE IDS (not edge ids): agg reads them directly, no ei
// indirection (R11/R12-measured: agg -2 to -4 us, FETCH -4MB)
__global__ void scatter_kernel(const int* __restrict__ ei, const int* __restrict__ indptr,
                               int* __restrict__ cur, int* __restrict__ sorted) {
    int e = blockIdx.x * 256 + threadIdx.x;
    if (e < E_TOT) {
        int d = edge_dst(ei, e);
        int pos = atomicAdd(&cur[d], 1);
        sorted[indptr[d] + pos] = edge_src(ei, e);
    }
}

// ---------------------------------------------------------------------------
// 320x256 fp16 MFMA GEMM (R8/R12 MEASURED champion loop, verbatim):
// Gray-code quadrants, wait-at-phase-start COUNTED vmcnt (4/5/5/none steady |
// 4/2/0/none final), stage groups {A012 | B01 | B23 | A34}, one barrier per
// phase, NO manual lgkmcnt drain (compiler emits fine-grained lgkmcnt per
// consuming MFMA), sched_barrier(0) after each s_barrier only.
// Requires K%64==0, K/64>=2, Nn%256==0, Mpad%320==0, nwg%8==0.
// ---------------------------------------------------------------------------
__global__ __launch_bounds__(512, 2) void gemm8p_kernel(
    const _Float16* __restrict__ A, const _Float16* __restrict__ B,
    _Float16* __restrict__ C, int M, int K, int Nn)
{
    __shared__ __align__(16) _Float16 lds[2][36864];   // 2 x (20480 A + 16384 B) = 144 KiB

    const int t = threadIdx.x;
    const int w = t >> 6, lane = t & 63;
    const int fr = lane & 15, q4 = lane >> 4;
    const int wr = w >> 2, wc = w & 3;        // 2 x 4 wave grid

    // bijective XCD chunk swizzle (nwg == 256, %8 == 0)
    const int nwgx = gridDim.x;
    int wg = blockIdx.y * nwgx + blockIdx.x;
    const int cpx = (nwgx * gridDim.y) >> 3;
    wg = (wg & 7) * cpx + (wg >> 3);
    const int row0 = (wg / nwgx) * 320;
    const int col0 = (wg % nwgx) * 256;

    // staging: load q covers rows [q*64, q*64+64), thread t -> row q*64 + (t>>3),
    // 16B slot t&7; swizzled global column = ((t&7) ^ (row&7)) * 8 elements.
    const int rowt = t >> 3;
    const int scol = ((t & 7) ^ (rowt & 7)) << 3;
    const _Float16* baseA = A + (size_t)(row0 + rowt) * K + scol;
    const _Float16* baseB = B + (size_t)(col0 + rowt) * K + scol;
    const int dstw = w * 512;                 // wave-uniform elem offset in a 4096-el load block

    auto stageA = [&](int q, int kel, int bb) {
        __builtin_amdgcn_global_load_lds(
            (const __attribute__((address_space(1))) void*)(baseA + (size_t)q * 64 * K + kel),
            (__attribute__((address_space(3))) void*)&lds[bb][q * 4096 + dstw], 16, 0, 0);
    };
    auto stageB = [&](int q, int kel, int bb) {
        __builtin_amdgcn_global_load_lds(
            (const __attribute__((address_space(1))) void*)(baseB + (size_t)q * 64 * K + kel),
            (__attribute__((address_space(3))) void*)&lds[bb][20480 + q * 4096 + dstw], 16, 0, 0);
    };

    f32x4 acc[2][2][5][2];
#pragma unroll
    for (int qm = 0; qm < 2; qm++)
#pragma unroll
        for (int qn = 0; qn < 2; qn++)
#pragma unroll
            for (int mi = 0; mi < 5; mi++)
#pragma unroll
                for (int ni = 0; ni < 2; ni++)
                    acc[qm][qn][mi][ni] = {0.f, 0.f, 0.f, 0.f};

    // persistent operand fragments (Gray-code reuse across phases)
    f16x8 fa[5][2], fb[2][2];

#define LOADA(BB, QM)                                                           \
    {                                                                           \
        _Pragma("unroll")                                                       \
        for (int ks = 0; ks < 2; ks++) {                                        \
            _Pragma("unroll")                                                   \
            for (int mi = 0; mi < 5; mi++) {                                    \
                int lr = wr * 80 + mi * 16 + fr;                                \
                int sl = ((ks << 2) | q4) ^ (fr & 7);                           \
                fa[mi][ks] = *(const f16x8*)&lds[BB][(QM) * 10240 + (lr << 6) + (sl << 3)]; \
            }                                                                   \
        }                                                                       \
    }
#define LOADB(BB, QN)                                                           \
    {                                                                           \
        _Pragma("unroll")                                                       \
        for (int ks = 0; ks < 2; ks++) {                                        \
            _Pragma("unroll")                                                   \
            for (int ni = 0; ni < 2; ni++) {                                    \
                int lr = wc * 32 + ni * 16 + fr;                                \
                int sl = ((ks << 2) | q4) ^ (fr & 7);                           \
                fb[ni][ks] = *(const f16x8*)&lds[BB][20480 + (QN) * 8192 + (lr << 6) + (sl << 3)]; \
            }                                                                   \
        }                                                                       \
    }

#define PHASE(QM, QN, LOAD_STMT, STAGE_STMT, WAIT_STMT)                         \
    do {                                                                        \
        WAIT_STMT;                                                              \
        __builtin_amdgcn_s_barrier();                                           \
        __builtin_amdgcn_sched_barrier(0);                                      \
        LOAD_STMT;                                                              \
        STAGE_STMT;                                                             \
        _Pragma("unroll")                                                       \
        for (int ks = 0; ks < 2; ks++) {                                        \
            _Pragma("unroll")                                                   \
            for (int mi = 0; mi < 5; mi++) {                                    \
                _Pragma("unroll")                                               \
                for (int ni = 0; ni < 2; ni++)                                  \
                    acc[QM][QN][mi][ni] = __builtin_amdgcn_mfma_f32_16x16x32_f16(\
                        fa[mi][ks], fb[ni][ks], acc[QM][QN][mi][ni], 0, 0, 0);  \
            }                                                                   \
        }                                                                       \
    } while (0)

#define VM(N) asm volatile("s_waitcnt vmcnt(" #N ")" ::: "memory")

    // prologue: stage tile 0 in wait-group order {A012, B01, B23, A34}
    stageA(0, 0, 0); stageA(1, 0, 0); stageA(2, 0, 0);
    stageB(0, 0, 0); stageB(1, 0, 0);
    stageB(2, 0, 0); stageB(3, 0, 0);
    stageA(3, 0, 0); stageA(4, 0, 0);

    const int nT = K >> 6;
    int t0 = 0;
    for (; t0 < nT - 1; ++t0) {
        int bb = t0 & 1;
        int bn = bb ^ 1;
        int k1 = (t0 + 1) << 6;
        PHASE(0, 0, { LOADA(bb, 0); LOADB(bb, 0); },
              { stageA(0, k1, bn); stageA(1, k1, bn); stageA(2, k1, bn); },
              VM(4));
        PHASE(0, 1, { LOADB(bb, 1); },
              { stageB(0, k1, bn); stageB(1, k1, bn); },
              VM(5));
        PHASE(1, 1, { LOADA(bb, 1); },
              { stageB(2, k1, bn); stageB(3, k1, bn); },
              VM(5));
        PHASE(1, 0, { LOADB(bb, 0); },
              { stageA(3, k1, bn); stageA(4, k1, bn); },
              ((void)0));
    }
    {   // final tile: no prefetch; exact residual drains
        int bb = t0 & 1;
        PHASE(0, 0, { LOADA(bb, 0); LOADB(bb, 0); }, ((void)0), VM(4));
        PHASE(0, 1, { LOADB(bb, 1); },               ((void)0), VM(2));
        PHASE(1, 1, { LOADA(bb, 1); },               ((void)0), VM(0));
        PHASE(1, 0, { LOADB(bb, 0); },               ((void)0), ((void)0));
    }
#undef PHASE
#undef LOADA
#undef LOADB
#undef VM

    // C/D layout (measured m89/m91): col = lane&15, row = quad*4 + reg
#pragma unroll
    for (int qm = 0; qm < 2; qm++)
#pragma unroll
        for (int qn = 0; qn < 2; qn++)
#pragma unroll
            for (int mi = 0; mi < 5; mi++) {
                int mb = row0 + qm * 160 + wr * 80 + mi * 16 + q4 * 4;
#pragma unroll
                for (int ni = 0; ni < 2; ni++) {
                    int n = col0 + qn * 128 + wc * 32 + ni * 16 + fr;
#pragma unroll
                    for (int r = 0; r < 4; r++) {
                        int m = mb + r;
                        if (m < M) C[(size_t)m * Nn + n] = (_Float16)acc[qm][qn][mi][ni][r];
                    }
                }
            }
}

// ---------------------------------------------------------------------------
// fp16 MFMA GEMM (128x128, BK=32, dbuf) — kept for the small projection GEMM
// (Nn=256 is too narrow for the 8-phase kernel).  EPI=1: fp32 relu(C + bias).
// ---------------------------------------------------------------------------
template <int EPI>
__global__ __launch_bounds__(256) void mfma_gemm_kernel(
    const _Float16* __restrict__ A, const _Float16* __restrict__ B,
    void* __restrict__ Cout, const float* __restrict__ bias,
    int M, int K, int Nn, int swz)
{
    __shared__ __align__(16) _Float16 sA[2][128 * 32];   // 2 x 8 KB
    __shared__ __align__(16) _Float16 sB[2][128 * 32];   // 2 x 8 KB

    int t = threadIdx.x;
    int bx = blockIdx.x, by = blockIdx.y;
    if (swz) {                       // gridDim.x == 16 only
        int id = by * 16 + bx;
        int xcd = id & 7, slot = id >> 3;
        bx = 2 * xcd + (slot & 1);
        by = slot >> 1;
    }
    int row0 = by * 128;
    int col0 = bx * 128;

    int s0 = t, s1 = t + 256;
    int m0 = s0 >> 2, k0 = (s0 & 3) * 8;
    int m1 = s1 >> 2, k1 = (s1 & 3) * 8;
    const _Float16* a0 = A + (size_t)(row0 + m0) * K + k0;
    const _Float16* a1 = A + (size_t)(row0 + m1) * K + k1;
    const _Float16* b0 = B + (size_t)(col0 + m0) * K + k0;
    const _Float16* b1 = B + (size_t)(col0 + m1) * K + k1;

    int w = t >> 6, lane = t & 63;
    int wm = (w & 1) * 64, wn = (w >> 1) * 64;
    int fr = lane & 15, quad = lane >> 4;

    auto stage = [&](int kt, int bsel) {
        _Float16* dA0 = &sA[bsel][(w * 64) * 8];
        _Float16* dA1 = &sA[bsel][(w * 64 + 256) * 8];
        _Float16* dB0 = &sB[bsel][(w * 64) * 8];
        _Float16* dB1 = &sB[bsel][(w * 64 + 256) * 8];
        __builtin_amdgcn_global_load_lds(
            (const __attribute__((address_space(1))) void*)(a0 + kt),
            (__attribute__((address_space(3))) void*)dA0, 16, 0, 0);
        __builtin_amdgcn_global_load_lds(
            (const __attribute__((address_space(1))) void*)(a1 + kt),
            (__attribute__((address_space(3))) void*)dA1, 16, 0, 0);
        __builtin_amdgcn_global_load_lds(
            (const __attribute__((address_space(1))) void*)(b0 + kt),
            (__attribute__((address_space(3))) void*)dB0, 16, 0, 0);
        __builtin_amdgcn_global_load_lds(
            (const __attribute__((address_space(1))) void*)(b1 + kt),
            (__attribute__((address_space(3))) void*)dB1, 16, 0, 0);
    };

    f32x4 acc[4][4];
#pragma unroll
    for (int i = 0; i < 4; i++)
#pragma unroll
        for (int j = 0; j < 4; j++) acc[i][j] = {0.f, 0.f, 0.f, 0.f};

    const int nIt = K / 32;
    stage(0, 0);
    __syncthreads();

    for (int it = 0; it < nIt; ++it) {
        int cb = it & 1;
        if (it + 1 < nIt) stage((it + 1) * 32, cb ^ 1);

        f16x8 fa[4], fb[4];
#pragma unroll
        for (int i = 0; i < 4; i++) {
            fa[i] = *(const f16x8*)&sA[cb][(wm + i * 16 + fr) * 32 + quad * 8];
            fb[i] = *(const f16x8*)&sB[cb][(wn + i * 16 + fr) * 32 + quad * 8];
        }
#pragma unroll
        for (int i = 0; i < 4; i++)
#pragma unroll
            for (int j = 0; j < 4; j++)
                acc[i][j] = __builtin_amdgcn_mfma_f32_16x16x32_f16(fa[i], fb[j], acc[i][j], 0, 0, 0);

        if (it + 1 < nIt) __syncthreads();
    }

    if (EPI == 0) {
        _Float16* C = (_Float16*)Cout;
#pragma unroll
        for (int i = 0; i < 4; i++) {
            int mbase = row0 + wm + i * 16 + quad * 4;
#pragma unroll
            for (int j = 0; j < 4; j++) {
                int n = col0 + wn + j * 16 + fr;
#pragma unroll
                for (int r = 0; r < 4; r++) {
                    int m = mbase + r;
                    if (m < M) C[(size_t)m * Nn + n] = (_Float16)acc[i][j][r];
                }
            }
        }
    } else {
        float* C = (float*)Cout;
        float bv[4];
#pragma unroll
        for (int j = 0; j < 4; j++) bv[j] = bias[col0 + wn + j * 16 + fr];
#pragma unroll
        for (int i = 0; i < 4; i++) {
            int mbase = row0 + wm + i * 16 + quad * 4;
#pragma unroll
            for (int j = 0; j < 4; j++) {
                int n = col0 + wn + j * 16 + fr;
#pragma unroll
                for (int r = 0; r < 4; r++) {
                    int m = mbase + r;
                    if (m < M) C[(size_t)m * Nn + n] = fmaxf(acc[i][j][r] + bv[j], 0.f);
                }
            }
        }
    }
}

// ---------------------------------------------------------------------------
// per-node attention coefficients from fp16 H (R4/R8 champion config)
// ---------------------------------------------------------------------------
__global__ __launch_bounds__(256) void attn_kernel(
    const _Float16* __restrict__ H, const float* __restrict__ a_src,
    const float* __restrict__ a_dst, float* __restrict__ as_out,
    float* __restrict__ ad_out)
{
    int n = blockIdx.x;
    int t = threadIdx.x;
    int h = t >> 5, l = t & 31;
    f16x8 hv = *(const f16x8*)&H[(size_t)n * HC + h * HID + l * 8];
    const float* asp = a_src + h * HID + l * 8;
    const float* adp = a_dst + h * HID + l * 8;
    float sa = 0.f, sd = 0.f;
#pragma unroll
    for (int q = 0; q < 8; q++) {
        float v = (float)hv[q];
        sa = fmaf(v, asp[q], sa);
        sd = fmaf(v, adp[q], sd);
    }
#pragma unroll
    for (int o = 16; o > 0; o >>= 1) {
        sa += __shfl_xor(sa, o, 32);
        sd += __shfl_xor(sd, o, 32);
    }
    if (l == 0) { as_out[n * HEADS + h] = sa; ad_out[n * HEADS + h] = sd; }
}

// ---------------------------------------------------------------------------
// per-dst-node gather aggregation with segment softmax (R12 champion base).
// Round-13: fast-path alpha stage loads sorted[start+j] DIRECTLY per thread
// (4x redundant across groups -> same address, L2/coalescer broadcast)
// instead of bouncing through srcl LDS; group 0 stores srcl for the gather.
// Removes one __syncthreads and one LDS round-trip from the per-block serial
// chain (3 barriers -> 2).  FP op order per element unchanged.
// MODE 0: elu(sum + b1) -> fp16 [MPAD, HC]
// MODE 1: (mean over heads + b2) -> fp16 [MPAD, HID]
// ---------------------------------------------------------------------------
template <int MODE>
__global__ __launch_bounds__(256) void agg_kernel(
    const _Float16* __restrict__ H, const float* __restrict__ as_,
    const float* __restrict__ ad_, const float* __restrict__ bias,
    const int* __restrict__ indptr, const int* __restrict__ sorted,
    _Float16* __restrict__ outh)
{
    __shared__ float m8[HEADS], d8[HEADS], adl[HEADS];
    __shared__ int   srcl[64];
    __shared__ float al2[HEADS][64];   // alpha, transposed: [head][edge]
    __shared__ float red[HC];          // MODE 1 cross-head reduction

    int n = blockIdx.x;
    int t = threadIdx.x;

    if (n >= NNODES) {                 // pad rows for the next MFMA GEMM
        if (MODE == 0) {
            _Float16 z8[8] = {};
            *(f16x8*)&outh[(size_t)n * HC + t * 8] = *(f16x8*)z8;
        } else {
            outh[(size_t)n * HID + t] = (_Float16)0.f;
        }
        return;
    }

    int start = indptr[n];
    int deg = indptr[n + 1] - start;

    if (t < HEADS) adl[t] = ad_[n * HEADS + t];
    __syncthreads();

    int hh = t >> 5, c8 = (t & 31) * 8;
    const size_t hoff = (size_t)hh * HID + c8;
    float acc[8] = {};

    if (deg <= 64) {
        // ---- merged src+alpha stage: each group loads sorted directly ----
        {
            int j = t & 63, h0 = t >> 6;          // h0 in 0..3
            if (j < deg) {
                int s = sorted[start + j];        // L2 broadcast across groups
                if (h0 == 0) srcl[j] = s;         // for the gather phase
#pragma unroll
                for (int q = 0; q < 2; q++) {
                    int hx = h0 + q * 4;
                    float v = as_[s * HEADS + hx] + adl[hx];
                    v = (v >= 0.f) ? v : NEG_SLOPE * v;
                    al2[hx][j] = v;
                }
            }
        }
        __syncthreads();
        {
            int h = t >> 5, l = t & 31;
            float mx = -1e30f;
            for (int jj = l; jj < deg; jj += 32) mx = fmaxf(mx, al2[h][jj]);
#pragma unroll
            for (int o = 16; o > 0; o >>= 1) mx = fmaxf(mx, __shfl_xor(mx, o, 32));
            float sm = 0.f;
            for (int jj = l; jj < deg; jj += 32) {
                float e = expf(al2[h][jj] - mx);
                al2[h][jj] = e;
                sm += e;
            }
#pragma unroll
            for (int o = 16; o > 0; o >>= 1) sm += __shfl_xor(sm, o, 32);
            float den = sm + 1e-16f;
            for (int jj = l; jj < deg; jj += 32) al2[h][jj] = al2[h][jj] / den;
        }
        __syncthreads();
        // ---- gather: 4 edges per step, alpha via one float4 LDS read ----
        int jj = 0;
        for (; jj + 3 < deg; jj += 4) {
            int sx0 = srcl[jj + 0], sx1 = srcl[jj + 1];
            int sx2 = srcl[jj + 2], sx3 = srcl[jj + 3];
            f16x8 h0v = *(const f16x8*)&H[(size_t)sx0 * HC + hoff];
            f16x8 h1v = *(const f16x8*)&H[(size_t)sx1 * HC + hoff];
            f16x8 h2v = *(const f16x8*)&H[(size_t)sx2 * HC + hoff];
            f16x8 h3v = *(const f16x8*)&H[(size_t)sx3 * HC + hoff];
            float4 a4 = *(const float4*)&al2[hh][jj];
#pragma unroll
            for (int q = 0; q < 8; q++) acc[q] = fmaf(a4.x, (float)h0v[q], acc[q]);
#pragma unroll
            for (int q = 0; q < 8; q++) acc[q] = fmaf(a4.y, (float)h1v[q], acc[q]);
#pragma unroll
            for (int q = 0; q < 8; q++) acc[q] = fmaf(a4.z, (float)h2v[q], acc[q]);
#pragma unroll
            for (int q = 0; q < 8; q++) acc[q] = fmaf(a4.w, (float)h3v[q], acc[q]);
        }
        for (; jj < deg; jj++) {
            int s = srcl[jj];
            f16x8 hv = *(const f16x8*)&H[(size_t)s * HC + hoff];
            float a = al2[hh][jj];
#pragma unroll
            for (int q = 0; q < 8; q++)
                acc[q] = fmaf(a, (float)hv[q], acc[q]);
        }
    } else {
        // ---- general chunked path (deg > 64, rare) ----
        int h = t >> 5, l = t & 31;
        float adh = adl[h];

        float mx = -1e30f;
        for (int j = l; j < deg; j += 32) {
            int s = sorted[start + j];
            float v = as_[s * HEADS + h] + adh;
            v = (v >= 0.f) ? v : NEG_SLOPE * v;
            mx = fmaxf(mx, v);
        }
#pragma unroll
        for (int o = 16; o > 0; o >>= 1) mx = fmaxf(mx, __shfl_xor(mx, o, 32));

        float sm = 0.f;
        for (int j = l; j < deg; j += 32) {
            int s = sorted[start + j];
            float v = as_[s * HEADS + h] + adh;
            v = (v >= 0.f) ? v : NEG_SLOPE * v;
            sm += expf(v - mx);
        }
#pragma unroll
        for (int o = 16; o > 0; o >>= 1) sm += __shfl_xor(sm, o, 32);
        if (l == 0) { m8[h] = mx; d8[h] = sm; }

        for (int base = 0; base < deg; base += 64) {
            int cntc = min(64, deg - base);
            __syncthreads();
            if (t < cntc) srcl[t] = sorted[start + base + t];
            __syncthreads();
            {
                int j = t & 63, h0 = t >> 6;
                if (j < cntc) {
                    int s = srcl[j];
#pragma unroll
                    for (int q = 0; q < 2; q++) {
                        int hx = h0 + q * 4;
                        float v = as_[s * HEADS + hx] + adl[hx];
                        v = (v >= 0.f) ? v : NEG_SLOPE * v;
                        al2[hx][j] = expf(v - m8[hx]) / (d8[hx] + 1e-16f);
                    }
                }
            }
            __syncthreads();
            int jj = 0;
            for (; jj + 3 < cntc; jj += 4) {
                int sx0 = srcl[jj + 0], sx1 = srcl[jj + 1];
                int sx2 = srcl[jj + 2], sx3 = srcl[jj + 3];
                f16x8 h0v = *(const f16x8*)&H[(size_t)sx0 * HC + hoff];
                f16x8 h1v = *(const f16x8*)&H[(size_t)sx1 * HC + hoff];
                f16x8 h2v = *(const f16x8*)&H[(size_t)sx2 * HC + hoff];
                f16x8 h3v = *(const f16x8*)&H[(size_t)sx3 * HC + hoff];
                float4 a4 = *(const float4*)&al2[hh][jj];
#pragma unroll
                for (int q = 0; q < 8; q++) acc[q] = fmaf(a4.x, (float)h0v[q], acc[q]);
#pragma unroll
                for (int q = 0; q < 8; q++) acc[q] = fmaf(a4.y, (float)h1v[q], acc[q]);
#pragma unroll
                for (int q = 0; q < 8; q++) acc[q] = fmaf(a4.z, (float)h2v[q], acc[q]);
#pragma unroll
                for (int q = 0; q < 8; q++) acc[q] = fmaf(a4.w, (float)h3v[q], acc[q]);
            }
            for (; jj < cntc; jj++) {
                int s = srcl[jj];
                f16x8 hv = *(const f16x8*)&H[(size_t)s * HC + hoff];
                float a = al2[hh][jj];
#pragma unroll
                for (int q = 0; q < 8; q++)
                    acc[q] = fmaf(a, (float)hv[q], acc[q]);
            }
        }
    }

    if (MODE == 0) {
        _Float16 o8[8];
#pragma unroll
        for (int q = 0; q < 8; q++) {
            float v = acc[q] + bias[hoff + q];
            v = (v > 0.f) ? v : expm1f(v);          // ELU (alpha=1)
            o8[q] = (_Float16)v;
        }
        *(f16x8*)&outh[(size_t)n * HC + hoff] = *(f16x8*)o8;
    } else {
#pragma unroll
        for (int q = 0; q < 8; q++) red[hoff + q] = acc[q];
        __syncthreads();
        float s = 0.f;
#pragma unroll
        for (int h2 = 0; h2 < HEADS; h2++) s += red[h2 * HID + t];
        outh[(size_t)n * HID + t] = (_Float16)(s * 0.125f + bias[t]);
    }
}

// ---------------------------------------------------------------------------
extern "C" void kernel_launch(void* const* d_in, const int* in_sizes, int n_in,
                              void* d_out, int out_size, void* d_ws, size_t ws_size,
                              hipStream_t stream)
{
    const float* x      = (const float*)d_in[0];
    const int*   ei     = (const int*)  d_in[1];
    const float* W1     = (const float*)d_in[2];
    const float* a_src1 = (const float*)d_in[3];
    const float* a_dst1 = (const float*)d_in[4];
    const float* b1     = (const float*)d_in[5];
    const float* W2     = (const float*)d_in[6];
    const float* a_src2 = (const float*)d_in[7];
    const float* a_dst2 = (const float*)d_in[8];
    const float* b2     = (const float*)d_in[9];
    const float* Wp     = (const float*)d_in[10];
    const float* bp     = (const float*)d_in[11];
    float* out = (float*)d_out;

    char* ws = (char*)d_ws;
    size_t off = 0;
    auto alloc = [&](size_t bytes) -> char* {
        char* p = ws + off;
        off += (bytes + 255) & ~(size_t)255;
        return p;
    };
    _Float16* Hbuf = (_Float16*)alloc((size_t)NNODES * HC * 2);          // 41 MB (H1, then H2)
    _Float16* A2   = (_Float16*)alloc((size_t)MPAD * HC * 2);            // 41.9 MB
    _Float16* W1t  = (_Float16*)alloc((size_t)HC * IN_DIM * 2);          // 3.1 MB
    _Float16* W2t  = (_Float16*)alloc((size_t)HC * HC * 2);              // 8.4 MB
    _Float16* Wpt  = (_Float16*)alloc((size_t)HID * HID * 2);            // 128 KB
    _Float16* xh   = (_Float16*)alloc((size_t)MPAD * IN_DIM * 2);        // 15.7 MB
    _Float16* out2h = (_Float16*)alloc((size_t)MPAD * HID * 2);          // 5.2 MB
    float* asad   = (float*)alloc((size_t)4 * NNODES * HEADS * sizeof(float));
    float* as1 = asad;
    float* ad1 = asad + (size_t)NNODES * HEADS;
    float* as2 = asad + (size_t)2 * NNODES * HEADS;
    float* ad2 = asad + (size_t)3 * NNODES * HEADS;
    int*   cntcur = (int*)alloc((size_t)2 * NNODES * sizeof(int));   // cnt | cur contiguous
    int*   cnt = cntcur;
    int*   cur = cntcur + NNODES;
    int*   indptr = (int*)  alloc((size_t)(NNODES + 1) * sizeof(int));
    int*   sorted = (int*)  alloc((size_t)E_TOT * sizeof(int));

    // --- one memset for cnt+cur, then fused prep (cvt + count + 3 transposes)
    hipMemsetAsync(cntcur, 0, (size_t)2 * NNODES * sizeof(int), stream);
    prep_kernel<<<PREP_BLK, 256, 0, stream>>>(x, xh, ei, cnt,
                                              W1, W1t, W2, W2t, Wp, Wpt);
    scan_kernel<<<1, 1024, 0, stream>>>(cnt, indptr);
    scatter_kernel<<<(E_TOT + 255) / 256, 256, 0, stream>>>(ei, indptr, cur, sorted);

    dim3 g8(HC / 256, MPAD / 320);   // 8 x 32 = 256 blocks = one full round

    // Layer 1: H1 = x @ W1 (R8-champion 320x256 fp16 MFMA)
    gemm8p_kernel<<<g8, 512, 0, stream>>>(xh, W1t, Hbuf, NNODES, IN_DIM, HC);
    attn_kernel<<<NNODES, 256, 0, stream>>>(Hbuf, a_src1, a_dst1, as1, ad1);
    agg_kernel<0><<<MPAD, 256, 0, stream>>>(Hbuf, as1, ad1, b1, indptr, sorted, A2);

    // Layer 2: H2 = elu_agg @ W2 (R8-champion 320x256 fp16 MFMA)
    gemm8p_kernel<<<g8, 512, 0, stream>>>(A2, W2t, Hbuf, NNODES, HC, HC);
    attn_kernel<<<NNODES, 256, 0, stream>>>(Hbuf, a_src2, a_dst2, as2, ad2);
    agg_kernel<1><<<MPAD, 256, 0, stream>>>(Hbuf, as2, ad2, b2, indptr, sorted, out2h);

    // Projection + ReLU (128^2 fp16 MFMA, bias+relu fp32 epilogue)
    dim3 gProj(HID / 128, MPAD / 128);   // 2 x 80
    mfma_gemm_kernel<1><<<gProj, 256, 0, stream>>>(out2h, Wpt, out, bp,
                                                   NNODES, HID, HID, 0);
}

// Round 14
// 383.151 us; speedup vs baseline: 1.0894x; 1.0098x over previous
//
#include <hip/hip_runtime.h>
#include <cstdint>
#include <cstddef>

#define IN_DIM  768
#define NNODES  10000
#define MPAD    10240        // 32 * 320 (gemm8p) and 80 * 128 (proj GEMM)
#define NEDGES  80000
#define E_TOT   90000        // edges + self loops
#define HEADS   8
#define HID     256
#define HC      2048         // HEADS*HID
#define NEG_SLOPE 0.2f

// prep_kernel block ranges (256 threads each)
#define CVT_BLK  ((MPAD * IN_DIM / 4) / 256)          // 7680
#define CNT_BLK  ((E_TOT + 255) / 256)                // 352
#define T1_BLK   ((HC / 32) * (IN_DIM / 32))          // 1536
#define T2_BLK   ((HC / 32) * (HC / 32))              // 4096
#define TP_BLK   ((HID / 32) * (HID / 32))            // 64
#define PREP_BLK (CVT_BLK + CNT_BLK + T1_BLK + T2_BLK + TP_BLK)

typedef _Float16 __attribute__((ext_vector_type(8))) f16x8;
typedef float    __attribute__((ext_vector_type(4))) f32x4;

// ---------------------------------------------------------------------------
// edge helpers: edge ids [0,NEDGES) are real edges, [NEDGES,E_TOT) self loops
// ---------------------------------------------------------------------------
__device__ __forceinline__ int edge_src(const int* __restrict__ ei, int e) {
    return (e < NEDGES) ? ei[e] : (e - NEDGES);
}
__device__ __forceinline__ int edge_dst(const int* __restrict__ ei, int e) {
    return (e < NEDGES) ? ei[NEDGES + e] : (e - NEDGES);
}

// ---------------------------------------------------------------------------
// fused preprocessing (R9-proven): cvt + edge count + 3 weight transposes
// ---------------------------------------------------------------------------
__device__ __forceinline__ void tcvt_body(
    const float* __restrict__ W, _Float16* __restrict__ T,
    int K, int N, int bx, int by, int t)
{
    __shared__ float tile[32][33];
    int tx = t & 31, ty = t >> 5;   // 32 x 8
#pragma unroll
    for (int q = 0; q < 4; q++)
        tile[ty + q * 8][tx] = W[(size_t)(by * 32 + ty + q * 8) * N + bx * 32 + tx];
    __syncthreads();
#pragma unroll
    for (int q = 0; q < 4; q++) {
        float v = tile[tx][ty + q * 8];
        T[(size_t)(bx * 32 + ty + q * 8) * K + by * 32 + tx] = (_Float16)v;
    }
}

__global__ __launch_bounds__(256) void prep_kernel(
    const float* __restrict__ x, _Float16* __restrict__ xh,
    const int* __restrict__ ei, int* __restrict__ cnt,
    const float* __restrict__ W1, _Float16* __restrict__ W1t,
    const float* __restrict__ W2, _Float16* __restrict__ W2t,
    const float* __restrict__ Wp, _Float16* __restrict__ Wpt)
{
    int b = blockIdx.x;
    int t = threadIdx.x;
    if (b < CVT_BLK) {
        int i = b * 256 + t;
        size_t e = (size_t)i * 4;
        int r = (int)(e / IN_DIM);
        float4 v = (r < NNODES) ? *(const float4*)(x + e)
                                : make_float4(0.f, 0.f, 0.f, 0.f);
        _Float16 h4[4] = {(_Float16)v.x, (_Float16)v.y, (_Float16)v.z, (_Float16)v.w};
        *(ushort4*)(xh + e) = *(ushort4*)h4;
    } else if (b < CVT_BLK + CNT_BLK) {
        int e = (b - CVT_BLK) * 256 + t;
        if (e < E_TOT) atomicAdd(&cnt[edge_dst(ei, e)], 1);
    } else if (b < CVT_BLK + CNT_BLK + T1_BLK) {
        int idx = b - (CVT_BLK + CNT_BLK);
        tcvt_body(W1, W1t, IN_DIM, HC, idx % (HC / 32), idx / (HC / 32), t);
    } else if (b < CVT_BLK + CNT_BLK + T1_BLK + T2_BLK) {
        int idx = b - (CVT_BLK + CNT_BLK + T1_BLK);
        tcvt_body(W2, W2t, HC, HC, idx % (HC / 32), idx / (HC / 32), t);
    } else {
        int idx = b - (CVT_BLK + CNT_BLK + T1_BLK + T2_BLK);
        tcvt_body(Wp, Wpt, HID, HID, idx % (HID / 32), idx / (HID / 32), t);
    }
}

// ---------------------------------------------------------------------------
// CSR: scan + scatter (count fused into prep_kernel)
// ---------------------------------------------------------------------------
__global__ void scan_kernel(const int* __restrict__ cnt, int* __restrict__ indptr) {
    __shared__ int sums[1024];
    const int CH = 10;
    int t = threadIdx.x;
    int base = t * CH;
    int s = 0;
#pragma unroll
    for (int i = 0; i < CH; i++) { int idx = base + i; if (idx < NNODES) s += cnt[idx]; }
    sums[t] = s;
    __syncthreads();
    for (int off = 1; off < 1024; off <<= 1) {
        int v = (t >= off) ? sums[t - off] : 0;
        __syncthreads();
        sums[t] += v;
        __syncthreads();
    }
    int run = (t == 0) ? 0 : sums[t - 1];
#pragma unroll
    for (int i = 0; i < CH; i++) {
        int idx = base + i;
        if (idx < NNODES) { indptr[idx] = run; run += cnt[idx]; }
    }
    if (t == 0) indptr[NNODES] = E_TOT;
}

// stores SRC NODE IDS (not edge ids): agg reads them directly, no ei
// indirection (R11/R12-measured: agg -2 to -4 us, FETCH -4MB)
__global__ void scatter_kernel(const int* __restrict__ ei, const int* __restrict__ indptr,
                               int* __restrict__ cur, int* __restrict__ sorted) {
    int e = blockIdx.x * 256 + threadIdx.x;
    if (e < E_TOT) {
        int d = edge_dst(ei, e);
        int pos = atomicAdd(&cur[d], 1);
        sorted[indptr[d] + pos] = edge_src(ei, e);
    }
}

// ---------------------------------------------------------------------------
// 320x256 fp16 MFMA GEMM (R8/R12 MEASURED champion loop, verbatim):
// Gray-code quadrants, wait-at-phase-start COUNTED vmcnt (4/5/5/none steady |
// 4/2/0/none final), stage groups {A012 | B01 | B23 | A34}, one barrier per
// phase, NO manual lgkmcnt drain (compiler emits fine-grained lgkmcnt per
// consuming MFMA), sched_barrier(0) after each s_barrier only.
// Requires K%64==0, K/64>=2, Nn%256==0, Mpad%320==0, nwg%8==0.
// ---------------------------------------------------------------------------
__global__ __launch_bounds__(512, 2) void gemm8p_kernel(
    const _Float16* __restrict__ A, const _Float16* __restrict__ B,
    _Float16* __restrict__ C, int M, int K, int Nn)
{
    __shared__ __align__(16) _Float16 lds[2][36864];   // 2 x (20480 A + 16384 B) = 144 KiB

    const int t = threadIdx.x;
    const int w = t >> 6, lane = t & 63;
    const int fr = lane & 15, q4 = lane >> 4;
    const int wr = w >> 2, wc = w & 3;        // 2 x 4 wave grid

    // bijective XCD chunk swizzle (nwg == 256, %8 == 0)
    const int nwgx = gridDim.x;
    int wg = blockIdx.y * nwgx + blockIdx.x;
    const int cpx = (nwgx * gridDim.y) >> 3;
    wg = (wg & 7) * cpx + (wg >> 3);
    const int row0 = (wg / nwgx) * 320;
    const int col0 = (wg % nwgx) * 256;

    // staging: load q covers rows [q*64, q*64+64), thread t -> row q*64 + (t>>3),
    // 16B slot t&7; swizzled global column = ((t&7) ^ (row&7)) * 8 elements.
    const int rowt = t >> 3;
    const int scol = ((t & 7) ^ (rowt & 7)) << 3;
    const _Float16* baseA = A + (size_t)(row0 + rowt) * K + scol;
    const _Float16* baseB = B + (size_t)(col0 + rowt) * K + scol;
    const int dstw = w * 512;                 // wave-uniform elem offset in a 4096-el load block

    auto stageA = [&](int q, int kel, int bb) {
        __builtin_amdgcn_global_load_lds(
            (const __attribute__((address_space(1))) void*)(baseA + (size_t)q * 64 * K + kel),
            (__attribute__((address_space(3))) void*)&lds[bb][q * 4096 + dstw], 16, 0, 0);
    };
    auto stageB = [&](int q, int kel, int bb) {
        __builtin_amdgcn_global_load_lds(
            (const __attribute__((address_space(1))) void*)(baseB + (size_t)q * 64 * K + kel),
            (__attribute__((address_space(3))) void*)&lds[bb][20480 + q * 4096 + dstw], 16, 0, 0);
    };

    f32x4 acc[2][2][5][2];
#pragma unroll
    for (int qm = 0; qm < 2; qm++)
#pragma unroll
        for (int qn = 0; qn < 2; qn++)
#pragma unroll
            for (int mi = 0; mi < 5; mi++)
#pragma unroll
                for (int ni = 0; ni < 2; ni++)
                    acc[qm][qn][mi][ni] = {0.f, 0.f, 0.f, 0.f};

    // persistent operand fragments (Gray-code reuse across phases)
    f16x8 fa[5][2], fb[2][2];

#define LOADA(BB, QM)                                                           \
    {                                                                           \
        _Pragma("unroll")                                                       \
        for (int ks = 0; ks < 2; ks++) {                                        \
            _Pragma("unroll")                                                   \
            for (int mi = 0; mi < 5; mi++) {                                    \
                int lr = wr * 80 + mi * 16 + fr;                                \
                int sl = ((ks << 2) | q4) ^ (fr & 7);                           \
                fa[mi][ks] = *(const f16x8*)&lds[BB][(QM) * 10240 + (lr << 6) + (sl << 3)]; \
            }                                                                   \
        }                                                                       \
    }
#define LOADB(BB, QN)                                                           \
    {                                                                           \
        _Pragma("unroll")                                                       \
        for (int ks = 0; ks < 2; ks++) {                                        \
            _Pragma("unroll")                                                   \
            for (int ni = 0; ni < 2; ni++) {                                    \
                int lr = wc * 32 + ni * 16 + fr;                                \
                int sl = ((ks << 2) | q4) ^ (fr & 7);                           \
                fb[ni][ks] = *(const f16x8*)&lds[BB][20480 + (QN) * 8192 + (lr << 6) + (sl << 3)]; \
            }                                                                   \
        }                                                                       \
    }

#define PHASE(QM, QN, LOAD_STMT, STAGE_STMT, WAIT_STMT)                         \
    do {                                                                        \
        WAIT_STMT;                                                              \
        __builtin_amdgcn_s_barrier();                                           \
        __builtin_amdgcn_sched_barrier(0);                                      \
        LOAD_STMT;                                                              \
        STAGE_STMT;                                                             \
        _Pragma("unroll")                                                       \
        for (int ks = 0; ks < 2; ks++) {                                        \
            _Pragma("unroll")                                                   \
            for (int mi = 0; mi < 5; mi++) {                                    \
                _Pragma("unroll")                                               \
                for (int ni = 0; ni < 2; ni++)                                  \
                    acc[QM][QN][mi][ni] = __builtin_amdgcn_mfma_f32_16x16x32_f16(\
                        fa[mi][ks], fb[ni][ks], acc[QM][QN][mi][ni], 0, 0, 0);  \
            }                                                                   \
        }                                                                       \
    } while (0)

#define VM(N) asm volatile("s_waitcnt vmcnt(" #N ")" ::: "memory")

    // prologue: stage tile 0 in wait-group order {A012, B01, B23, A34}
    stageA(0, 0, 0); stageA(1, 0, 0); stageA(2, 0, 0);
    stageB(0, 0, 0); stageB(1, 0, 0);
    stageB(2, 0, 0); stageB(3, 0, 0);
    stageA(3, 0, 0); stageA(4, 0, 0);

    const int nT = K >> 6;
    int t0 = 0;
    for (; t0 < nT - 1; ++t0) {
        int bb = t0 & 1;
        int bn = bb ^ 1;
        int k1 = (t0 + 1) << 6;
        PHASE(0, 0, { LOADA(bb, 0); LOADB(bb, 0); },
              { stageA(0, k1, bn); stageA(1, k1, bn); stageA(2, k1, bn); },
              VM(4));
        PHASE(0, 1, { LOADB(bb, 1); },
              { stageB(0, k1, bn); stageB(1, k1, bn); },
              VM(5));
        PHASE(1, 1, { LOADA(bb, 1); },
              { stageB(2, k1, bn); stageB(3, k1, bn); },
              VM(5));
        PHASE(1, 0, { LOADB(bb, 0); },
              { stageA(3, k1, bn); stageA(4, k1, bn); },
              ((void)0));
    }
    {   // final tile: no prefetch; exact residual drains
        int bb = t0 & 1;
        PHASE(0, 0, { LOADA(bb, 0); LOADB(bb, 0); }, ((void)0), VM(4));
        PHASE(0, 1, { LOADB(bb, 1); },               ((void)0), VM(2));
        PHASE(1, 1, { LOADA(bb, 1); },               ((void)0), VM(0));
        PHASE(1, 0, { LOADB(bb, 0); },               ((void)0), ((void)0));
    }
#undef PHASE
#undef LOADA
#undef LOADB
#undef VM

    // C/D layout (measured m89/m91): col = lane&15, row = quad*4 + reg
#pragma unroll
    for (int qm = 0; qm < 2; qm++)
#pragma unroll
        for (int qn = 0; qn < 2; qn++)
#pragma unroll
            for (int mi = 0; mi < 5; mi++) {
                int mb = row0 + qm * 160 + wr * 80 + mi * 16 + q4 * 4;
#pragma unroll
                for (int ni = 0; ni < 2; ni++) {
                    int n = col0 + qn * 128 + wc * 32 + ni * 16 + fr;
#pragma unroll
                    for (int r = 0; r < 4; r++) {
                        int m = mb + r;
                        if (m < M) C[(size_t)m * Nn + n] = (_Float16)acc[qm][qn][mi][ni][r];
                    }
                }
            }
}

// ---------------------------------------------------------------------------
// fp16 MFMA GEMM (128x128, BK=32, dbuf) — kept for the small projection GEMM
// (Nn=256 is too narrow for the 8-phase kernel).  EPI=1: fp32 relu(C + bias).
// ---------------------------------------------------------------------------
template <int EPI>
__global__ __launch_bounds__(256) void mfma_gemm_kernel(
    const _Float16* __restrict__ A, const _Float16* __restrict__ B,
    void* __restrict__ Cout, const float* __restrict__ bias,
    int M, int K, int Nn, int swz)
{
    __shared__ __align__(16) _Float16 sA[2][128 * 32];   // 2 x 8 KB
    __shared__ __align__(16) _Float16 sB[2][128 * 32];   // 2 x 8 KB

    int t = threadIdx.x;
    int bx = blockIdx.x, by = blockIdx.y;
    if (swz) {                       // gridDim.x == 16 only
        int id = by * 16 + bx;
        int xcd = id & 7, slot = id >> 3;
        bx = 2 * xcd + (slot & 1);
        by = slot >> 1;
    }
    int row0 = by * 128;
    int col0 = bx * 128;

    int s0 = t, s1 = t + 256;
    int m0 = s0 >> 2, k0 = (s0 & 3) * 8;
    int m1 = s1 >> 2, k1 = (s1 & 3) * 8;
    const _Float16* a0 = A + (size_t)(row0 + m0) * K + k0;
    const _Float16* a1 = A + (size_t)(row0 + m1) * K + k1;
    const _Float16* b0 = B + (size_t)(col0 + m0) * K + k0;
    const _Float16* b1 = B + (size_t)(col0 + m1) * K + k1;

    int w = t >> 6, lane = t & 63;
    int wm = (w & 1) * 64, wn = (w >> 1) * 64;
    int fr = lane & 15, quad = lane >> 4;

    auto stage = [&](int kt, int bsel) {
        _Float16* dA0 = &sA[bsel][(w * 64) * 8];
        _Float16* dA1 = &sA[bsel][(w * 64 + 256) * 8];
        _Float16* dB0 = &sB[bsel][(w * 64) * 8];
        _Float16* dB1 = &sB[bsel][(w * 64 + 256) * 8];
        __builtin_amdgcn_global_load_lds(
            (const __attribute__((address_space(1))) void*)(a0 + kt),
            (__attribute__((address_space(3))) void*)dA0, 16, 0, 0);
        __builtin_amdgcn_global_load_lds(
            (const __attribute__((address_space(1))) void*)(a1 + kt),
            (__attribute__((address_space(3))) void*)dA1, 16, 0, 0);
        __builtin_amdgcn_global_load_lds(
            (const __attribute__((address_space(1))) void*)(b0 + kt),
            (__attribute__((address_space(3))) void*)dB0, 16, 0, 0);
        __builtin_amdgcn_global_load_lds(
            (const __attribute__((address_space(1))) void*)(b1 + kt),
            (__attribute__((address_space(3))) void*)dB1, 16, 0, 0);
    };

    f32x4 acc[4][4];
#pragma unroll
    for (int i = 0; i < 4; i++)
#pragma unroll
        for (int j = 0; j < 4; j++) acc[i][j] = {0.f, 0.f, 0.f, 0.f};

    const int nIt = K / 32;
    stage(0, 0);
    __syncthreads();

    for (int it = 0; it < nIt; ++it) {
        int cb = it & 1;
        if (it + 1 < nIt) stage((it + 1) * 32, cb ^ 1);

        f16x8 fa[4], fb[4];
#pragma unroll
        for (int i = 0; i < 4; i++) {
            fa[i] = *(const f16x8*)&sA[cb][(wm + i * 16 + fr) * 32 + quad * 8];
            fb[i] = *(const f16x8*)&sB[cb][(wn + i * 16 + fr) * 32 + quad * 8];
        }
#pragma unroll
        for (int i = 0; i < 4; i++)
#pragma unroll
            for (int j = 0; j < 4; j++)
                acc[i][j] = __builtin_amdgcn_mfma_f32_16x16x32_f16(fa[i], fb[j], acc[i][j], 0, 0, 0);

        if (it + 1 < nIt) __syncthreads();
    }

    if (EPI == 0) {
        _Float16* C = (_Float16*)Cout;
#pragma unroll
        for (int i = 0; i < 4; i++) {
            int mbase = row0 + wm + i * 16 + quad * 4;
#pragma unroll
            for (int j = 0; j < 4; j++) {
                int n = col0 + wn + j * 16 + fr;
#pragma unroll
                for (int r = 0; r < 4; r++) {
                    int m = mbase + r;
                    if (m < M) C[(size_t)m * Nn + n] = (_Float16)acc[i][j][r];
                }
            }
        }
    } else {
        float* C = (float*)Cout;
        float bv[4];
#pragma unroll
        for (int j = 0; j < 4; j++) bv[j] = bias[col0 + wn + j * 16 + fr];
#pragma unroll
        for (int i = 0; i < 4; i++) {
            int mbase = row0 + wm + i * 16 + quad * 4;
#pragma unroll
            for (int j = 0; j < 4; j++) {
                int n = col0 + wn + j * 16 + fr;
#pragma unroll
                for (int r = 0; r < 4; r++) {
                    int m = mbase + r;
                    if (m < M) C[(size_t)m * Nn + n] = fmaxf(acc[i][j][r] + bv[j], 0.f);
                }
            }
        }
    }
}

// ---------------------------------------------------------------------------
// per-node attention coefficients from fp16 H (R4/R8 champion config)
// ---------------------------------------------------------------------------
__global__ __launch_bounds__(256) void attn_kernel(
    const _Float16* __restrict__ H, const float* __restrict__ a_src,
    const float* __restrict__ a_dst, float* __restrict__ as_out,
    float* __restrict__ ad_out)
{
    int n = blockIdx.x;
    int t = threadIdx.x;
    int h = t >> 5, l = t & 31;
    f16x8 hv = *(const f16x8*)&H[(size_t)n * HC + h * HID + l * 8];
    const float* asp = a_src + h * HID + l * 8;
    const float* adp = a_dst + h * HID + l * 8;
    float sa = 0.f, sd = 0.f;
#pragma unroll
    for (int q = 0; q < 8; q++) {
        float v = (float)hv[q];
        sa = fmaf(v, asp[q], sa);
        sd = fmaf(v, adp[q], sd);
    }
#pragma unroll
    for (int o = 16; o > 0; o >>= 1) {
        sa += __shfl_xor(sa, o, 32);
        sd += __shfl_xor(sd, o, 32);
    }
    if (l == 0) { as_out[n * HEADS + h] = sa; ad_out[n * HEADS + h] = sd; }
}

// ---------------------------------------------------------------------------
// per-dst-node gather aggregation with segment softmax (R13 champion base).
// Round-14: fast-path softmax fully IN-WAVE.  Thread mapping j=t&63, h0=t>>6
// means wave w holds heads {w, w+4} raw alphas in REGISTERS, one edge/lane ->
// max/sum are 64-wide intra-wave shfl_xor trees (no LDS, no barrier), and
// ad_[n*8+w] is wave-uniform (direct load, no adl staging).  al2 is written
// once, already normalized.  Fast-path barriers 3 -> 1 (publish srcl+al2 to
// the gather's different mapping).  Per-element FP ops unchanged; only the
// reduce-tree is 64-wide vs 32-wide (R10 precedent: same absmax).
// MODE 0: elu(sum + b1) -> fp16 [MPAD, HC]
// MODE 1: (mean over heads + b2) -> fp16 [MPAD, HID]
// ---------------------------------------------------------------------------
template <int MODE>
__global__ __launch_bounds__(256) void agg_kernel(
    const _Float16* __restrict__ H, const float* __restrict__ as_,
    const float* __restrict__ ad_, const float* __restrict__ bias,
    const int* __restrict__ indptr, const int* __restrict__ sorted,
    _Float16* __restrict__ outh)
{
    __shared__ float m8[HEADS], d8[HEADS], adl[HEADS];
    __shared__ int   srcl[64];
    __shared__ float al2[HEADS][64];   // alpha (normalized): [head][edge]
    __shared__ float red[HC];          // MODE 1 cross-head reduction

    int n = blockIdx.x;
    int t = threadIdx.x;

    if (n >= NNODES) {                 // pad rows for the next MFMA GEMM
        if (MODE == 0) {
            _Float16 z8[8] = {};
            *(f16x8*)&outh[(size_t)n * HC + t * 8] = *(f16x8*)z8;
        } else {
            outh[(size_t)n * HID + t] = (_Float16)0.f;
        }
        return;
    }

    int start = indptr[n];
    int deg = indptr[n + 1] - start;

    int hh = t >> 5, c8 = (t & 31) * 8;
    const size_t hoff = (size_t)hh * HID + c8;
    float acc[8] = {};

    if (deg <= 64) {
        // ---- single-pass in-wave alpha+softmax: wave wv owns heads wv,wv+4 ----
        const int lane = t & 63, wv = t >> 6;           // wave id 0..3
        const float ad0 = ad_[n * HEADS + wv];          // wave-uniform loads
        const float ad1 = ad_[n * HEADS + wv + 4];
        float v0 = -1e30f, v1 = -1e30f;
        if (lane < deg) {
            int s = sorted[start + lane];               // L2 broadcast across waves
            if (wv == 0) srcl[lane] = s;                // for the gather phase
            float a0 = as_[s * HEADS + wv];
            float a1 = as_[s * HEADS + wv + 4];
            v0 = a0 + ad0; v0 = (v0 >= 0.f) ? v0 : NEG_SLOPE * v0;
            v1 = a1 + ad1; v1 = (v1 >= 0.f) ? v1 : NEG_SLOPE * v1;
        }
        float m0 = v0, m1 = v1;
#pragma unroll
        for (int o = 32; o > 0; o >>= 1) {
            m0 = fmaxf(m0, __shfl_xor(m0, o, 64));
            m1 = fmaxf(m1, __shfl_xor(m1, o, 64));
        }
        float e0 = (lane < deg) ? expf(v0 - m0) : 0.f;
        float e1 = (lane < deg) ? expf(v1 - m1) : 0.f;
        float s0 = e0, s1 = e1;
#pragma unroll
        for (int o = 32; o > 0; o >>= 1) {
            s0 += __shfl_xor(s0, o, 64);
            s1 += __shfl_xor(s1, o, 64);
        }
        if (lane < deg) {
            al2[wv][lane]     = e0 / (s0 + 1e-16f);
            al2[wv + 4][lane] = e1 / (s1 + 1e-16f);
        }
        __syncthreads();                                // publish srcl + al2
        // ---- gather: 4 edges per step, alpha via one float4 LDS read ----
        int jj = 0;
        for (; jj + 3 < deg; jj += 4) {
            int sx0 = srcl[jj + 0], sx1 = srcl[jj + 1];
            int sx2 = srcl[jj + 2], sx3 = srcl[jj + 3];
            f16x8 h0v = *(const f16x8*)&H[(size_t)sx0 * HC + hoff];
            f16x8 h1v = *(const f16x8*)&H[(size_t)sx1 * HC + hoff];
            f16x8 h2v = *(const f16x8*)&H[(size_t)sx2 * HC + hoff];
            f16x8 h3v = *(const f16x8*)&H[(size_t)sx3 * HC + hoff];
            float4 a4 = *(const float4*)&al2[hh][jj];
#pragma unroll
            for (int q = 0; q < 8; q++) acc[q] = fmaf(a4.x, (float)h0v[q], acc[q]);
#pragma unroll
            for (int q = 0; q < 8; q++) acc[q] = fmaf(a4.y, (float)h1v[q], acc[q]);
#pragma unroll
            for (int q = 0; q < 8; q++) acc[q] = fmaf(a4.z, (float)h2v[q], acc[q]);
#pragma unroll
            for (int q = 0; q < 8; q++) acc[q] = fmaf(a4.w, (float)h3v[q], acc[q]);
        }
        for (; jj < deg; jj++) {
            int s = srcl[jj];
            f16x8 hv = *(const f16x8*)&H[(size_t)s * HC + hoff];
            float a = al2[hh][jj];
#pragma unroll
            for (int q = 0; q < 8; q++)
                acc[q] = fmaf(a, (float)hv[q], acc[q]);
        }
    } else {
        // ---- general chunked path (deg > 64, rare; uniform branch) ----
        if (t < HEADS) adl[t] = ad_[n * HEADS + t];
        __syncthreads();
        int h = t >> 5, l = t & 31;
        float adh = adl[h];

        float mx = -1e30f;
        for (int j = l; j < deg; j += 32) {
            int s = sorted[start + j];
            float v = as_[s * HEADS + h] + adh;
            v = (v >= 0.f) ? v : NEG_SLOPE * v;
            mx = fmaxf(mx, v);
        }
#pragma unroll
        for (int o = 16; o > 0; o >>= 1) mx = fmaxf(mx, __shfl_xor(mx, o, 32));

        float sm = 0.f;
        for (int j = l; j < deg; j += 32) {
            int s = sorted[start + j];
            float v = as_[s * HEADS + h] + adh;
            v = (v >= 0.f) ? v : NEG_SLOPE * v;
            sm += expf(v - mx);
        }
#pragma unroll
        for (int o = 16; o > 0; o >>= 1) sm += __shfl_xor(sm, o, 32);
        if (l == 0) { m8[h] = mx; d8[h] = sm; }

        for (int base = 0; base < deg; base += 64) {
            int cntc = min(64, deg - base);
            __syncthreads();
            if (t < cntc) srcl[t] = sorted[start + base + t];
            __syncthreads();
            {
                int j = t & 63, h0 = t >> 6;
                if (j < cntc) {
                    int s = srcl[j];
#pragma unroll
                    for (int q = 0; q < 2; q++) {
                        int hx = h0 + q * 4;
                        float v = as_[s * HEADS + hx] + adl[hx];
                        v = (v >= 0.f) ? v : NEG_SLOPE * v;
                        al2[hx][j] = expf(v - m8[hx]) / (d8[hx] + 1e-16f);
                    }
                }
            }
            __syncthreads();
            int jj = 0;
            for (; jj + 3 < cntc; jj += 4) {
                int sx0 = srcl[jj + 0], sx1 = srcl[jj + 1];
                int sx2 = srcl[jj + 2], sx3 = srcl[jj + 3];
                f16x8 h0v = *(const f16x8*)&H[(size_t)sx0 * HC + hoff];
                f16x8 h1v = *(const f16x8*)&H[(size_t)sx1 * HC + hoff];
                f16x8 h2v = *(const f16x8*)&H[(size_t)sx2 * HC + hoff];
                f16x8 h3v = *(const f16x8*)&H[(size_t)sx3 * HC + hoff];
                float4 a4 = *(const float4*)&al2[hh][jj];
#pragma unroll
                for (int q = 0; q < 8; q++) acc[q] = fmaf(a4.x, (float)h0v[q], acc[q]);
#pragma unroll
                for (int q = 0; q < 8; q++) acc[q] = fmaf(a4.y, (float)h1v[q], acc[q]);
#pragma unroll
                for (int q = 0; q < 8; q++) acc[q] = fmaf(a4.z, (float)h2v[q], acc[q]);
#pragma unroll
                for (int q = 0; q < 8; q++) acc[q] = fmaf(a4.w, (float)h3v[q], acc[q]);
            }
            for (; jj < cntc; jj++) {
                int s = srcl[jj];
                f16x8 hv = *(const f16x8*)&H[(size_t)s * HC + hoff];
                float a = al2[hh][jj];
#pragma unroll
                for (int q = 0; q < 8; q++)
                    acc[q] = fmaf(a, (float)hv[q], acc[q]);
            }
        }
    }

    if (MODE == 0) {
        _Float16 o8[8];
#pragma unroll
        for (int q = 0; q < 8; q++) {
            float v = acc[q] + bias[hoff + q];
            v = (v > 0.f) ? v : expm1f(v);          // ELU (alpha=1)
            o8[q] = (_Float16)v;
        }
        *(f16x8*)&outh[(size_t)n * HC + hoff] = *(f16x8*)o8;
    } else {
#pragma unroll
        for (int q = 0; q < 8; q++) red[hoff + q] = acc[q];
        __syncthreads();
        float s = 0.f;
#pragma unroll
        for (int h2 = 0; h2 < HEADS; h2++) s += red[h2 * HID + t];
        outh[(size_t)n * HID + t] = (_Float16)(s * 0.125f + bias[t]);
    }
}

// ---------------------------------------------------------------------------
extern "C" void kernel_launch(void* const* d_in, const int* in_sizes, int n_in,
                              void* d_out, int out_size, void* d_ws, size_t ws_size,
                              hipStream_t stream)
{
    const float* x      = (const float*)d_in[0];
    const int*   ei     = (const int*)  d_in[1];
    const float* W1     = (const float*)d_in[2];
    const float* a_src1 = (const float*)d_in[3];
    const float* a_dst1 = (const float*)d_in[4];
    const float* b1     = (const float*)d_in[5];
    const float* W2     = (const float*)d_in[6];
    const float* a_src2 = (const float*)d_in[7];
    const float* a_dst2 = (const float*)d_in[8];
    const float* b2     = (const float*)d_in[9];
    const float* Wp     = (const float*)d_in[10];
    const float* bp     = (const float*)d_in[11];
    float* out = (float*)d_out;

    char* ws = (char*)d_ws;
    size_t off = 0;
    auto alloc = [&](size_t bytes) -> char* {
        char* p = ws + off;
        off += (bytes + 255) & ~(size_t)255;
        return p;
    };
    _Float16* Hbuf = (_Float16*)alloc((size_t)NNODES * HC * 2);          // 41 MB (H1, then H2)
    _Float16* A2   = (_Float16*)alloc((size_t)MPAD * HC * 2);            // 41.9 MB
    _Float16* W1t  = (_Float16*)alloc((size_t)HC * IN_DIM * 2);          // 3.1 MB
    _Float16* W2t  = (_Float16*)alloc((size_t)HC * HC * 2);              // 8.4 MB
    _Float16* Wpt  = (_Float16*)alloc((size_t)HID * HID * 2);            // 128 KB
    _Float16* xh   = (_Float16*)alloc((size_t)MPAD * IN_DIM * 2);        // 15.7 MB
    _Float16* out2h = (_Float16*)alloc((size_t)MPAD * HID * 2);          // 5.2 MB
    float* asad   = (float*)alloc((size_t)4 * NNODES * HEADS * sizeof(float));
    float* as1 = asad;
    float* ad1 = asad + (size_t)NNODES * HEADS;
    float* as2 = asad + (size_t)2 * NNODES * HEADS;
    float* ad2 = asad + (size_t)3 * NNODES * HEADS;
    int*   cntcur = (int*)alloc((size_t)2 * NNODES * sizeof(int));   // cnt | cur contiguous
    int*   cnt = cntcur;
    int*   cur = cntcur + NNODES;
    int*   indptr = (int*)  alloc((size_t)(NNODES + 1) * sizeof(int));
    int*   sorted = (int*)  alloc((size_t)E_TOT * sizeof(int));

    // --- one memset for cnt+cur, then fused prep (cvt + count + 3 transposes)
    hipMemsetAsync(cntcur, 0, (size_t)2 * NNODES * sizeof(int), stream);
    prep_kernel<<<PREP_BLK, 256, 0, stream>>>(x, xh, ei, cnt,
                                              W1, W1t, W2, W2t, Wp, Wpt);
    scan_kernel<<<1, 1024, 0, stream>>>(cnt, indptr);
    scatter_kernel<<<(E_TOT + 255) / 256, 256, 0, stream>>>(ei, indptr, cur, sorted);

    dim3 g8(HC / 256, MPAD / 320);   // 8 x 32 = 256 blocks = one full round

    // Layer 1: H1 = x @ W1 (R8-champion 320x256 fp16 MFMA)
    gemm8p_kernel<<<g8, 512, 0, stream>>>(xh, W1t, Hbuf, NNODES, IN_DIM, HC);
    attn_kernel<<<NNODES, 256, 0, stream>>>(Hbuf, a_src1, a_dst1, as1, ad1);
    agg_kernel<0><<<MPAD, 256, 0, stream>>>(Hbuf, as1, ad1, b1, indptr, sorted, A2);

    // Layer 2: H2 = elu_agg @ W2 (R8-champion 320x256 fp16 MFMA)
    gemm8p_kernel<<<g8, 512, 0, stream>>>(A2, W2t, Hbuf, NNODES, HC, HC);
    attn_kernel<<<NNODES, 256, 0, stream>>>(Hbuf, a_src2, a_dst2, as2, ad2);
    agg_kernel<1><<<MPAD, 256, 0, stream>>>(Hbuf, as2, ad2, b2, indptr, sorted, out2h);

    // Projection + ReLU (128^2 fp16 MFMA, bias+relu fp32 epilogue)
    dim3 gProj(HID / 128, MPAD / 128);   // 2 x 80
    mfma_gemm_kernel<1><<<gProj, 256, 0, stream>>>(out2h, Wpt, out, bp,
                                                   NNODES, HID, HID, 0);
}